// Round 10
// baseline (593.330 us; speedup 1.0000x reference)
//
#include <hip/hip_runtime.h>
#include <hip/hip_fp16.h>
#include <cstdint>

#define N_NODES 50000
#define B_SZ 4
#define C_IN 32
#define C_OUT 64
#define K_CHEB 6
#define M_POOL 12500
#define NT_ROWS (N_NODES + M_POOL)
#define NS32 ((size_t)N_NODES * C_IN)
#define ZH ((size_t)N_NODES * C_OUT)   // z elements per batch (fp16)

typedef _Float16 f16x8 __attribute__((ext_vector_type(8)));
typedef float f32x4 __attribute__((ext_vector_type(4)));
typedef unsigned short ushort_t;

__device__ __forceinline__ unsigned short f2h(float f) {
    union { _Float16 h; unsigned short u; } v;
    v.h = (_Float16)f;
    return v.u;
}

__device__ __forceinline__ float h2f(unsigned short u) {
    union { unsigned short u; _Float16 h; } v;
    v.u = u;
    return (float)v.h;
}

__device__ __forceinline__ __half2 u2h2(unsigned u) { return __builtin_bit_cast(__half2, u); }
__device__ __forceinline__ unsigned h22u(__half2 h) { return __builtin_bit_cast(unsigned, h); }

// ---------------- Combined CSR build (rows 0..N-1 = graph, N..N+M-1 = pool) ----------------
__global__ void deg_slot_kernel(const int* __restrict__ row, const int* __restrict__ prow,
                                int* __restrict__ deg, int* __restrict__ slot, int E, int P) {
    int e = blockIdx.x * blockDim.x + threadIdx.x;
    if (e < E) slot[e] = atomicAdd(&deg[row[e]], 1);
    else if (e < E + P) slot[e] = atomicAdd(&deg[N_NODES + prow[e - E]], 1);
}

// dis for graph rows; padded degree: graph rows pad to multiple of 4, pool rows unpadded
__global__ void disdegp_kernel(const int* __restrict__ deg, float* __restrict__ dis,
                               int* __restrict__ degp) {
    int i = blockIdx.x * blockDim.x + threadIdx.x;
    if (i < N_NODES) {
        int d = deg[i];
        dis[i] = d > 0 ? rsqrtf((float)d) : 0.f;
        degp[i] = (d + 3) & ~3;
    } else if (i < NT_ROWS) {
        degp[i] = deg[i];
    }
}

__global__ void block_sum_kernel(const int* __restrict__ degp, int* __restrict__ bsum, int N) {
    __shared__ int sm[256];
    int i = blockIdx.x * 256 + threadIdx.x;
    sm[threadIdx.x] = (i < N) ? degp[i] : 0;
    __syncthreads();
    for (int s = 128; s > 0; s >>= 1) {
        if (threadIdx.x < s) sm[threadIdx.x] += sm[threadIdx.x + s];
        __syncthreads();
    }
    if (threadIdx.x == 0) bsum[blockIdx.x] = sm[0];
}

__global__ void scan_bsum_kernel(int* bsum, int nb, int* rowptr, int N) {
    if (blockIdx.x == 0 && threadIdx.x == 0) {
        int run = 0;
        for (int i = 0; i < nb; i++) { int v = bsum[i]; bsum[i] = run; run += v; }
        rowptr[N] = run;
    }
}

__global__ void rowptr_kernel(const int* __restrict__ degp, const int* __restrict__ bsum,
                              int* __restrict__ rowptr, int N) {
    __shared__ int sm[256];
    int i = blockIdx.x * 256 + threadIdx.x;
    sm[threadIdx.x] = (i < N) ? degp[i] : 0;
    __syncthreads();
    if (threadIdx.x == 0) {
        int run = bsum[blockIdx.x];
        for (int t = 0; t < 256; t++) { int v = sm[t]; sm[t] = run; run += v; }
    }
    __syncthreads();
    if (i < N) rowptr[i] = sm[threadIdx.x];
}

// atomic-free placement. Graph rows: cn.y = packed half2(norm,norm). Pool rows: cn.y = f32 bits.
__global__ void place_all_kernel(const int* __restrict__ row, const int* __restrict__ col,
                                 const int* __restrict__ prow, const int* __restrict__ pcol,
                                 const float* __restrict__ pval, const float* __restrict__ dis,
                                 const int* __restrict__ rowptr, const int* __restrict__ slot,
                                 int2* __restrict__ cn, int E, int P) {
    int e = blockIdx.x * blockDim.x + threadIdx.x;
    if (e < E) {
        int r = row[e], c = col[e];
        float nm = -dis[r] * dis[c];
        unsigned h = f2h(nm);
        cn[rowptr[r] + slot[e]] = make_int2(c, (int)(h | (h << 16)));
    } else if (e < E + P) {
        int i = e - E;
        int r = N_NODES + prow[i];
        cn[rowptr[r] + slot[e]] = make_int2(pcol[i], __float_as_int(pval[i]));
    }
}

// ---------------- degree counting sort (64 bins) -> ord[] row order ----------------
__global__ void hist_kernel(const int* __restrict__ deg, int* __restrict__ hist) {
    int i = blockIdx.x * blockDim.x + threadIdx.x;
    if (i < N_NODES) {
        int d = deg[i];
        atomicAdd(&hist[d < 63 ? d : 63], 1);
    }
}

__global__ void scan_hist_kernel(int* hist) {
    if (blockIdx.x == 0 && threadIdx.x == 0) {
        int run = 0;
        for (int i = 0; i < 64; i++) { int v = hist[i]; hist[i] = run; run += v; }
    }
}

__global__ void scatter_ord_kernel(const int* __restrict__ deg, int* __restrict__ hist,
                                   int* __restrict__ ord) {
    int i = blockIdx.x * blockDim.x + threadIdx.x;
    if (i < N_NODES) {
        int d = deg[i];
        int pos = atomicAdd(&hist[d < 63 ? d : 63], 1);
        ord[pos] = i;
    }
}

// ---------------- fp32 -> fp16 cast ----------------
__global__ void cast_h_kernel(const float* __restrict__ in, unsigned int* __restrict__ out,
                              int n2) {
    int i = blockIdx.x * 256 + threadIdx.x;
    if (i < n2) {
        unsigned a = f2h(in[2 * i]), b = f2h(in[2 * i + 1]);
        out[i] = a | (b << 16);
    }
}

// ---------------- Chebyshev propagation v10 ----------------
// thread = (row, channel-oct): 4 lanes/row, 16B feature loads (8 ch = 4 half2);
// rows processed in degree-sorted order (ord) -> uniform waves; rows padded to x4;
// 4-edge software pipeline; block = 64 rows of ONE batch (bid&3 -> L2 slice affinity).
__global__ void prop_kernel(const ushort_t* __restrict__ hf, const ushort_t* __restrict__ p2f,
                            ushort_t* __restrict__ outf,
                            const int* __restrict__ rowptr, const int* __restrict__ ord,
                            const int2* __restrict__ cn, float alpha) {
    int bid = blockIdx.x;
    int b = bid & 3;
    int grp = bid >> 2;            // [0, 782)
    int lr = threadIdx.x >> 2;     // 0..63
    int cs = threadIdx.x & 3;      // channel oct: channels 8cs .. 8cs+7
    int ri = grp * 64 + lr;
    if (ri >= N_NODES) return;
    int rr = ord[ri];
    const char* hb = (const char*)hf + (size_t)b * NS32 * 2;
    unsigned coff = (unsigned)cs * 16u;
    int p0 = rowptr[rr], p1 = rowptr[rr + 1];
    __half2 a0 = __float2half2_rn(0.f), a1 = a0, a2 = a0, a3 = a0;
    if (p0 < p1) {
        int2 ea[4];
#pragma unroll
        for (int i = 0; i < 4; i++) ea[i] = cn[p0 + i];
        for (int p = p0 + 4; p < p1; p += 4) {
            uint4 v[4];
#pragma unroll
            for (int i = 0; i < 4; i++)
                v[i] = *(const uint4*)(hb + (((unsigned)ea[i].x << 6) + coff));
            int2 eb[4];
#pragma unroll
            for (int i = 0; i < 4; i++) eb[i] = cn[p + i];
#pragma unroll
            for (int i = 0; i < 4; i++) {
                __half2 n2 = u2h2((unsigned)ea[i].y);
                a0 = __hfma2(u2h2(v[i].x), n2, a0);
                a1 = __hfma2(u2h2(v[i].y), n2, a1);
                a2 = __hfma2(u2h2(v[i].z), n2, a2);
                a3 = __hfma2(u2h2(v[i].w), n2, a3);
            }
#pragma unroll
            for (int i = 0; i < 4; i++) ea[i] = eb[i];
        }
        uint4 v[4];
#pragma unroll
        for (int i = 0; i < 4; i++)
            v[i] = *(const uint4*)(hb + (((unsigned)ea[i].x << 6) + coff));
#pragma unroll
        for (int i = 0; i < 4; i++) {
            __half2 n2 = u2h2((unsigned)ea[i].y);
            a0 = __hfma2(u2h2(v[i].x), n2, a0);
            a1 = __hfma2(u2h2(v[i].y), n2, a1);
            a2 = __hfma2(u2h2(v[i].z), n2, a2);
            a3 = __hfma2(u2h2(v[i].w), n2, a3);
        }
    }
    unsigned ooff = ((unsigned)rr << 6) + coff;
    uint4 o;
    if (p2f) {
        __half2 al2 = __float2half2_rn(alpha);
        uint4 pv = *(const uint4*)((const char*)p2f + (size_t)b * NS32 * 2 + ooff);
        o.x = h22u(__hfma2(a0, al2, __hneg2(u2h2(pv.x))));
        o.y = h22u(__hfma2(a1, al2, __hneg2(u2h2(pv.y))));
        o.z = h22u(__hfma2(a2, al2, __hneg2(u2h2(pv.z))));
        o.w = h22u(__hfma2(a3, al2, __hneg2(u2h2(pv.w))));
    } else {
        o.x = h22u(a0); o.y = h22u(a1); o.z = h22u(a2); o.w = h22u(a3);
    }
    *(uint4*)((char*)outf + (size_t)b * NS32 * 2 + ooff) = o;
}

// ---------------- W pack: [s][t][lane][j] fp16 fragment order ----------------
__global__ void packW_kernel(const float* __restrict__ W, ushort_t* __restrict__ Wp) {
    int i = blockIdx.x * 256 + threadIdx.x;
    if (i >= K_CHEB * 4 * 64 * 8) return;
    int j = i & 7;
    int lane = (i >> 3) & 63;
    int t = (i >> 9) & 3;
    int s = i >> 11;
    int k = (lane >> 4) * 8 + j;
    int col = t * 16 + (lane & 15);
    Wp[i] = f2h(W[((size_t)s * C_IN + k) * C_OUT + col]);
}

// ---------------- Fused 3-source MFMA GEMM (fp16 in, f32 accum, fp16 z) ----------------
__global__ void gemm_mfma_kernel(const ushort_t* __restrict__ T0, const ushort_t* __restrict__ T1,
                                 const ushort_t* __restrict__ T2,
                                 const ushort_t* __restrict__ Wp,
                                 const float* __restrict__ bias, ushort_t* __restrict__ z,
                                 int second) {
    int lane = threadIdx.x & 63;
    int wave = (blockIdx.x << 2) + (threadIdx.x >> 6);
    int r0 = wave << 4;
    int ga = r0 + (lane & 15);
    int koff = (lane >> 4) * 8;
    const ushort_t* Ts[3] = {T0, T1, T2};

    f16x8 afr[3];
#pragma unroll
    for (int s = 0; s < 3; s++)
        afr[s] = *(const f16x8*)(Ts[s] + (size_t)ga * C_IN + koff);

    int orow = r0 + ((lane >> 4) << 2);
#pragma unroll
    for (int t = 0; t < 4; t++) {
        f32x4 acc = {0.f, 0.f, 0.f, 0.f};
#pragma unroll
        for (int s = 0; s < 3; s++) {
            f16x8 bfr = *(const f16x8*)(Wp + (((s << 2) + t) * 64 + lane) * 8);
            acc = __builtin_amdgcn_mfma_f32_16x16x32_f16(afr[s], bfr, acc, 0, 0, 0);
        }
        int col = (t << 4) + (lane & 15);
        float bv = bias[col];
#pragma unroll
        for (int rg = 0; rg < 4; rg++) {
            size_t idx = (size_t)(orow + rg) * C_OUT + col;
            float v = acc[rg];
            if (!second) {
                z[idx] = f2h(v + bv);
            } else {
                v += h2f(z[idx]);
                z[idx] = f2h(v > 0.f ? v : (expf(v) - 1.f));
            }
        }
    }
}

// ---------------- Pool: deterministic CSR gather-reduce (fp16 z, combined rowptr) ----------
__global__ void pool_csr_kernel(const ushort_t* __restrict__ z, const int* __restrict__ rowptr,
                                const int2* __restrict__ cn, float* __restrict__ out) {
    int r = blockIdx.x * 8 + (threadIdx.x >> 5);
    int c2 = threadIdx.x & 31;   // channels 2c2, 2c2+1
    if (r >= M_POOL) return;
    const char* zb = (const char*)z;
    unsigned coff = (unsigned)c2 << 2;
    float s00 = 0.f, s01 = 0.f, s10 = 0.f, s11 = 0.f;
    float s20 = 0.f, s21 = 0.f, s30 = 0.f, s31 = 0.f;
    int p0 = rowptr[N_NODES + r], p1 = rowptr[N_NODES + r + 1];
    for (int p = p0; p < p1; ++p) {
        int2 e = cn[p];
        float v = __int_as_float(e.y);
        unsigned off = ((unsigned)e.x << 7) + coff;  // z row = 128B
        unsigned u0 = *(const unsigned*)(zb + off);
        unsigned u1 = *(const unsigned*)(zb + ZH * 2 + off);
        unsigned u2 = *(const unsigned*)(zb + 2 * ZH * 2 + off);
        unsigned u3 = *(const unsigned*)(zb + 3 * ZH * 2 + off);
        s00 += h2f((ushort_t)u0) * v; s01 += h2f((ushort_t)(u0 >> 16)) * v;
        s10 += h2f((ushort_t)u1) * v; s11 += h2f((ushort_t)(u1 >> 16)) * v;
        s20 += h2f((ushort_t)u2) * v; s21 += h2f((ushort_t)(u2 >> 16)) * v;
        s30 += h2f((ushort_t)u3) * v; s31 += h2f((ushort_t)(u3 >> 16)) * v;
    }
    size_t idx = (size_t)r * C_OUT + 2 * c2;
    size_t bs = (size_t)M_POOL * C_OUT;
    *(float2*)&out[idx]          = make_float2(s00, s01);
    *(float2*)&out[idx + bs]     = make_float2(s10, s11);
    *(float2*)&out[idx + 2 * bs] = make_float2(s20, s21);
    *(float2*)&out[idx + 3 * bs] = make_float2(s30, s31);
}

extern "C" void kernel_launch(void* const* d_in, const int* in_sizes, int n_in,
                              void* d_out, int out_size, void* d_ws, size_t ws_size,
                              hipStream_t stream) {
    const float* x    = (const float*)d_in[0];
    const int*   ei   = (const int*)d_in[1];
    const int*   prow = (const int*)d_in[2];
    const int*   pcol = (const int*)d_in[3];
    const float* pval = (const float*)d_in[4];
    const float* W    = (const float*)d_in[5];
    const float* bias = (const float*)d_in[6];
    const int E = in_sizes[1] / 2;
    const int P = in_sizes[2];
    const int* row = ei;
    const int* col = ei + E;
    const int EP_MAX = E + 3 * N_NODES + P;  // 4-padded CSR upper bound

    char* ws = (char*)d_ws;
    size_t o = 0;
    auto alloc = [&](size_t bytes) -> char* {
        char* p = ws + o;
        o += (bytes + 255) & ~(size_t)255;
        return p;
    };
    int nb = (NT_ROWS + 255) / 256;
    int*   deg    = (int*)alloc((size_t)NT_ROWS * 4);
    int*   degp   = (int*)alloc((size_t)NT_ROWS * 4);
    float* dis    = (float*)alloc((size_t)N_NODES * 4);
    int*   rowptr = (int*)alloc((size_t)(NT_ROWS + 1) * 4);
    int*   slot   = (int*)alloc((size_t)(E + P) * 4);
    int*   bsum   = (int*)alloc((size_t)nb * 4);
    int*   hist   = (int*)alloc(64 * 4);
    int*   ord    = (int*)alloc((size_t)N_NODES * 4);
    int2*  cn     = (int2*)alloc((size_t)EP_MAX * 8);
    ushort_t* Wp  = (ushort_t*)alloc((size_t)K_CHEB * 4 * 64 * 8 * 2);
    ushort_t* xh  = (ushort_t*)alloc((size_t)B_SZ * NS32 * 2);
    ushort_t* hA  = (ushort_t*)alloc((size_t)B_SZ * NS32 * 2);
    ushort_t* hB  = (ushort_t*)alloc((size_t)B_SZ * NS32 * 2);
    ushort_t* hC  = (ushort_t*)alloc((size_t)B_SZ * NS32 * 2);
    ushort_t* z   = (ushort_t*)alloc((size_t)B_SZ * ZH * 2);

    hipMemsetAsync(deg, 0, (size_t)NT_ROWS * 4, stream);
    hipMemsetAsync(hist, 0, 64 * 4, stream);
    hipMemsetAsync(cn, 0, (size_t)EP_MAX * 8, stream);  // pad entries -> col 0, norm 0.0

    // combined CSR build (single atomic pass; atomicAdd return = slot)
    deg_slot_kernel<<<(E + P + 255) / 256, 256, 0, stream>>>(row, prow, deg, slot, E, P);
    disdegp_kernel<<<nb, 256, 0, stream>>>(deg, dis, degp);
    block_sum_kernel<<<nb, 256, 0, stream>>>(degp, bsum, NT_ROWS);
    scan_bsum_kernel<<<1, 64, 0, stream>>>(bsum, nb, rowptr, NT_ROWS);
    rowptr_kernel<<<nb, 256, 0, stream>>>(degp, bsum, rowptr, NT_ROWS);
    place_all_kernel<<<(E + P + 255) / 256, 256, 0, stream>>>(row, col, prow, pcol, pval, dis,
                                                              rowptr, slot, cn, E, P);
    // degree counting sort -> ord
    hist_kernel<<<(N_NODES + 255) / 256, 256, 0, stream>>>(deg, hist);
    scan_hist_kernel<<<1, 64, 0, stream>>>(hist);
    scatter_ord_kernel<<<(N_NODES + 255) / 256, 256, 0, stream>>>(deg, hist, ord);
    // W pack + x cast
    packW_kernel<<<(K_CHEB * 4 * 64 * 8 + 255) / 256, 256, 0, stream>>>(W, Wp);
    int n2 = (int)(B_SZ * NS32 / 2);
    cast_h_kernel<<<(n2 + 255) / 256, 256, 0, stream>>>(x, (unsigned int*)xh, n2);

    int prop_blocks = ((N_NODES + 63) / 64) * B_SZ;  // 782 * 4 = 3128
    int gemm_blocks = (B_SZ * N_NODES) / 64;         // 3125

    // T1 = prop(x); T2 = 2*prop(T1) - x
    prop_kernel<<<prop_blocks, 256, 0, stream>>>(xh, nullptr, hA, rowptr, ord, cn, 1.0f);
    prop_kernel<<<prop_blocks, 256, 0, stream>>>(hA, xh, hB, rowptr, ord, cn, 2.0f);
    // z = [x,T1,T2] @ W[0:3] + bias
    gemm_mfma_kernel<<<gemm_blocks, 256, 0, stream>>>(xh, hA, hB, Wp, bias, z, 0);
    // T3, T4, T5
    prop_kernel<<<prop_blocks, 256, 0, stream>>>(hB, hA, hC, rowptr, ord, cn, 2.0f);
    prop_kernel<<<prop_blocks, 256, 0, stream>>>(hC, hB, hA, rowptr, ord, cn, 2.0f);
    prop_kernel<<<prop_blocks, 256, 0, stream>>>(hA, hC, hB, rowptr, ord, cn, 2.0f);
    // z = ELU(z + [T3,T4,T5] @ W[3:6])
    gemm_mfma_kernel<<<gemm_blocks, 256, 0, stream>>>(hC, hA, hB, Wp + 3 * 4 * 64 * 8,
                                                      bias, z, 1);
    // pool
    pool_csr_kernel<<<(M_POOL + 7) / 8, 256, 0, stream>>>(z, rowptr, cn, (float*)d_out);
}

// Round 11
// 308.852 us; speedup vs baseline: 1.9211x; 1.9211x over previous
//
#include <hip/hip_runtime.h>
#include <hip/hip_fp16.h>
#include <cstdint>

#define N_NODES 50000
#define B_SZ 4
#define C_IN 32
#define C_OUT 64
#define K_CHEB 6
#define M_POOL 12500
#define NT_ROWS (N_NODES + M_POOL)
#define NS32 ((size_t)N_NODES * C_IN)
#define ZH ((size_t)N_NODES * C_OUT)   // z elements per batch (fp16)

typedef _Float16 f16x8 __attribute__((ext_vector_type(8)));
typedef float f32x4 __attribute__((ext_vector_type(4)));
typedef unsigned short ushort_t;

__device__ __forceinline__ unsigned short f2h(float f) {
    union { _Float16 h; unsigned short u; } v;
    v.h = (_Float16)f;
    return v.u;
}

__device__ __forceinline__ float h2f(unsigned short u) {
    union { unsigned short u; _Float16 h; } v;
    v.u = u;
    return (float)v.h;
}

__device__ __forceinline__ __half2 u2h2(unsigned u) { return __builtin_bit_cast(__half2, u); }
__device__ __forceinline__ unsigned h22u(__half2 h) { return __builtin_bit_cast(unsigned, h); }

// ---------------- Combined CSR build (rows 0..N-1 = graph, N..N+M-1 = pool) ----------------
__global__ void deg_slot_kernel(const int* __restrict__ row, const int* __restrict__ prow,
                                int* __restrict__ deg, int* __restrict__ slot, int E, int P) {
    int e = blockIdx.x * blockDim.x + threadIdx.x;
    if (e < E) slot[e] = atomicAdd(&deg[row[e]], 1);
    else if (e < E + P) slot[e] = atomicAdd(&deg[N_NODES + prow[e - E]], 1);
}

// dis for graph rows; padded degree: graph rows pad to multiple of 4, pool rows unpadded
__global__ void disdegp_kernel(const int* __restrict__ deg, float* __restrict__ dis,
                               int* __restrict__ degp) {
    int i = blockIdx.x * blockDim.x + threadIdx.x;
    if (i < N_NODES) {
        int d = deg[i];
        dis[i] = d > 0 ? rsqrtf((float)d) : 0.f;
        degp[i] = (d + 3) & ~3;
    } else if (i < NT_ROWS) {
        degp[i] = deg[i];
    }
}

__global__ void block_sum_kernel(const int* __restrict__ degp, int* __restrict__ bsum, int N) {
    __shared__ int sm[256];
    int i = blockIdx.x * 256 + threadIdx.x;
    sm[threadIdx.x] = (i < N) ? degp[i] : 0;
    __syncthreads();
    for (int s = 128; s > 0; s >>= 1) {
        if (threadIdx.x < s) sm[threadIdx.x] += sm[threadIdx.x + s];
        __syncthreads();
    }
    if (threadIdx.x == 0) bsum[blockIdx.x] = sm[0];
}

__global__ void scan_bsum_kernel(int* bsum, int nb, int* rowptr, int N) {
    if (blockIdx.x == 0 && threadIdx.x == 0) {
        int run = 0;
        for (int i = 0; i < nb; i++) { int v = bsum[i]; bsum[i] = run; run += v; }
        rowptr[N] = run;
    }
}

__global__ void rowptr_kernel(const int* __restrict__ degp, const int* __restrict__ bsum,
                              int* __restrict__ rowptr, int N) {
    __shared__ int sm[256];
    int i = blockIdx.x * 256 + threadIdx.x;
    sm[threadIdx.x] = (i < N) ? degp[i] : 0;
    __syncthreads();
    if (threadIdx.x == 0) {
        int run = bsum[blockIdx.x];
        for (int t = 0; t < 256; t++) { int v = sm[t]; sm[t] = run; run += v; }
    }
    __syncthreads();
    if (i < N) rowptr[i] = sm[threadIdx.x];
}

// atomic-free placement. Graph rows: cn.y = packed half2(norm,norm). Pool rows: cn.y = f32 bits.
__global__ void place_all_kernel(const int* __restrict__ row, const int* __restrict__ col,
                                 const int* __restrict__ prow, const int* __restrict__ pcol,
                                 const float* __restrict__ pval, const float* __restrict__ dis,
                                 const int* __restrict__ rowptr, const int* __restrict__ slot,
                                 int2* __restrict__ cn, int E, int P) {
    int e = blockIdx.x * blockDim.x + threadIdx.x;
    if (e < E) {
        int r = row[e], c = col[e];
        float nm = -dis[r] * dis[c];
        unsigned h = f2h(nm);
        cn[rowptr[r] + slot[e]] = make_int2(c, (int)(h | (h << 16)));
    } else if (e < E + P) {
        int i = e - E;
        int r = N_NODES + prow[i];
        cn[rowptr[r] + slot[e]] = make_int2(pcol[i], __float_as_int(pval[i]));
    }
}

// ---------------- fp32 -> fp16 cast ----------------
__global__ void cast_h_kernel(const float* __restrict__ in, unsigned int* __restrict__ out,
                              int n2) {
    int i = blockIdx.x * 256 + threadIdx.x;
    if (i < n2) {
        unsigned a = f2h(in[2 * i]), b = f2h(in[2 * i + 1]);
        out[i] = a | (b << 16);
    }
}

// ---------------- Chebyshev propagation v11 ----------------
// thread = (row, channel-oct): 4 lanes/row, 16B feature loads (8 ch = 4 half2);
// NATURAL row order (coalesced writes); rows padded to x4; 4-edge software pipeline;
// block = 64 rows of ONE batch (bid&3 -> per-XCD 3.2 MB batch slice stays L2-resident).
__global__ void prop_kernel(const ushort_t* __restrict__ hf, const ushort_t* __restrict__ p2f,
                            ushort_t* __restrict__ outf,
                            const int* __restrict__ rowptr, const int2* __restrict__ cn,
                            float alpha) {
    int bid = blockIdx.x;
    int b = bid & 3;
    int grp = bid >> 2;            // [0, 782)
    int lr = threadIdx.x >> 2;     // 0..63
    int cs = threadIdx.x & 3;      // channel oct: channels 8cs .. 8cs+7
    int r = grp * 64 + lr;
    if (r >= N_NODES) return;
    const char* hb = (const char*)hf + (size_t)b * NS32 * 2;
    unsigned coff = (unsigned)cs * 16u;
    int p0 = rowptr[r], p1 = rowptr[r + 1];
    __half2 a0 = __float2half2_rn(0.f), a1 = a0, a2 = a0, a3 = a0;
    if (p0 < p1) {
        int2 ea[4];
#pragma unroll
        for (int i = 0; i < 4; i++) ea[i] = cn[p0 + i];
        for (int p = p0 + 4; p < p1; p += 4) {
            uint4 v[4];
#pragma unroll
            for (int i = 0; i < 4; i++)
                v[i] = *(const uint4*)(hb + (((unsigned)ea[i].x << 6) + coff));
            int2 eb[4];
#pragma unroll
            for (int i = 0; i < 4; i++) eb[i] = cn[p + i];
#pragma unroll
            for (int i = 0; i < 4; i++) {
                __half2 n2 = u2h2((unsigned)ea[i].y);
                a0 = __hfma2(u2h2(v[i].x), n2, a0);
                a1 = __hfma2(u2h2(v[i].y), n2, a1);
                a2 = __hfma2(u2h2(v[i].z), n2, a2);
                a3 = __hfma2(u2h2(v[i].w), n2, a3);
            }
#pragma unroll
            for (int i = 0; i < 4; i++) ea[i] = eb[i];
        }
        uint4 v[4];
#pragma unroll
        for (int i = 0; i < 4; i++)
            v[i] = *(const uint4*)(hb + (((unsigned)ea[i].x << 6) + coff));
#pragma unroll
        for (int i = 0; i < 4; i++) {
            __half2 n2 = u2h2((unsigned)ea[i].y);
            a0 = __hfma2(u2h2(v[i].x), n2, a0);
            a1 = __hfma2(u2h2(v[i].y), n2, a1);
            a2 = __hfma2(u2h2(v[i].z), n2, a2);
            a3 = __hfma2(u2h2(v[i].w), n2, a3);
        }
    }
    unsigned ooff = ((unsigned)r << 6) + coff;
    uint4 o;
    if (p2f) {
        __half2 al2 = __float2half2_rn(alpha);
        uint4 pv = *(const uint4*)((const char*)p2f + (size_t)b * NS32 * 2 + ooff);
        o.x = h22u(__hfma2(a0, al2, __hneg2(u2h2(pv.x))));
        o.y = h22u(__hfma2(a1, al2, __hneg2(u2h2(pv.y))));
        o.z = h22u(__hfma2(a2, al2, __hneg2(u2h2(pv.z))));
        o.w = h22u(__hfma2(a3, al2, __hneg2(u2h2(pv.w))));
    } else {
        o.x = h22u(a0); o.y = h22u(a1); o.z = h22u(a2); o.w = h22u(a3);
    }
    *(uint4*)((char*)outf + (size_t)b * NS32 * 2 + ooff) = o;
}

// ---------------- W pack: [s][t][lane][j] fp16 fragment order ----------------
__global__ void packW_kernel(const float* __restrict__ W, ushort_t* __restrict__ Wp) {
    int i = blockIdx.x * 256 + threadIdx.x;
    if (i >= K_CHEB * 4 * 64 * 8) return;
    int j = i & 7;
    int lane = (i >> 3) & 63;
    int t = (i >> 9) & 3;
    int s = i >> 11;
    int k = (lane >> 4) * 8 + j;
    int col = t * 16 + (lane & 15);
    Wp[i] = f2h(W[((size_t)s * C_IN + k) * C_OUT + col]);
}

// ---------------- Fused 3-source MFMA GEMM (fp16 in, f32 accum, fp16 z) ----------------
__global__ void gemm_mfma_kernel(const ushort_t* __restrict__ T0, const ushort_t* __restrict__ T1,
                                 const ushort_t* __restrict__ T2,
                                 const ushort_t* __restrict__ Wp,
                                 const float* __restrict__ bias, ushort_t* __restrict__ z,
                                 int second) {
    int lane = threadIdx.x & 63;
    int wave = (blockIdx.x << 2) + (threadIdx.x >> 6);
    int r0 = wave << 4;
    int ga = r0 + (lane & 15);
    int koff = (lane >> 4) * 8;
    const ushort_t* Ts[3] = {T0, T1, T2};

    f16x8 afr[3];
#pragma unroll
    for (int s = 0; s < 3; s++)
        afr[s] = *(const f16x8*)(Ts[s] + (size_t)ga * C_IN + koff);

    int orow = r0 + ((lane >> 4) << 2);
#pragma unroll
    for (int t = 0; t < 4; t++) {
        f32x4 acc = {0.f, 0.f, 0.f, 0.f};
#pragma unroll
        for (int s = 0; s < 3; s++) {
            f16x8 bfr = *(const f16x8*)(Wp + (((s << 2) + t) * 64 + lane) * 8);
            acc = __builtin_amdgcn_mfma_f32_16x16x32_f16(afr[s], bfr, acc, 0, 0, 0);
        }
        int col = (t << 4) + (lane & 15);
        float bv = bias[col];
#pragma unroll
        for (int rg = 0; rg < 4; rg++) {
            size_t idx = (size_t)(orow + rg) * C_OUT + col;
            float v = acc[rg];
            if (!second) {
                z[idx] = f2h(v + bv);
            } else {
                v += h2f(z[idx]);
                z[idx] = f2h(v > 0.f ? v : (expf(v) - 1.f));
            }
        }
    }
}

// ---------------- Pool: deterministic CSR gather-reduce (fp16 z, combined rowptr) ----------
__global__ void pool_csr_kernel(const ushort_t* __restrict__ z, const int* __restrict__ rowptr,
                                const int2* __restrict__ cn, float* __restrict__ out) {
    int r = blockIdx.x * 8 + (threadIdx.x >> 5);
    int c2 = threadIdx.x & 31;   // channels 2c2, 2c2+1
    if (r >= M_POOL) return;
    const char* zb = (const char*)z;
    unsigned coff = (unsigned)c2 << 2;
    float s00 = 0.f, s01 = 0.f, s10 = 0.f, s11 = 0.f;
    float s20 = 0.f, s21 = 0.f, s30 = 0.f, s31 = 0.f;
    int p0 = rowptr[N_NODES + r], p1 = rowptr[N_NODES + r + 1];
    for (int p = p0; p < p1; ++p) {
        int2 e = cn[p];
        float v = __int_as_float(e.y);
        unsigned off = ((unsigned)e.x << 7) + coff;  // z row = 128B
        unsigned u0 = *(const unsigned*)(zb + off);
        unsigned u1 = *(const unsigned*)(zb + ZH * 2 + off);
        unsigned u2 = *(const unsigned*)(zb + 2 * ZH * 2 + off);
        unsigned u3 = *(const unsigned*)(zb + 3 * ZH * 2 + off);
        s00 += h2f((ushort_t)u0) * v; s01 += h2f((ushort_t)(u0 >> 16)) * v;
        s10 += h2f((ushort_t)u1) * v; s11 += h2f((ushort_t)(u1 >> 16)) * v;
        s20 += h2f((ushort_t)u2) * v; s21 += h2f((ushort_t)(u2 >> 16)) * v;
        s30 += h2f((ushort_t)u3) * v; s31 += h2f((ushort_t)(u3 >> 16)) * v;
    }
    size_t idx = (size_t)r * C_OUT + 2 * c2;
    size_t bs = (size_t)M_POOL * C_OUT;
    *(float2*)&out[idx]          = make_float2(s00, s01);
    *(float2*)&out[idx + bs]     = make_float2(s10, s11);
    *(float2*)&out[idx + 2 * bs] = make_float2(s20, s21);
    *(float2*)&out[idx + 3 * bs] = make_float2(s30, s31);
}

extern "C" void kernel_launch(void* const* d_in, const int* in_sizes, int n_in,
                              void* d_out, int out_size, void* d_ws, size_t ws_size,
                              hipStream_t stream) {
    const float* x    = (const float*)d_in[0];
    const int*   ei   = (const int*)d_in[1];
    const int*   prow = (const int*)d_in[2];
    const int*   pcol = (const int*)d_in[3];
    const float* pval = (const float*)d_in[4];
    const float* W    = (const float*)d_in[5];
    const float* bias = (const float*)d_in[6];
    const int E = in_sizes[1] / 2;
    const int P = in_sizes[2];
    const int* row = ei;
    const int* col = ei + E;
    const int EP_MAX = E + 3 * N_NODES + P;  // 4-padded CSR upper bound

    char* ws = (char*)d_ws;
    size_t o = 0;
    auto alloc = [&](size_t bytes) -> char* {
        char* p = ws + o;
        o += (bytes + 255) & ~(size_t)255;
        return p;
    };
    int nb = (NT_ROWS + 255) / 256;
    int*   deg    = (int*)alloc((size_t)NT_ROWS * 4);
    int*   degp   = (int*)alloc((size_t)NT_ROWS * 4);
    float* dis    = (float*)alloc((size_t)N_NODES * 4);
    int*   rowptr = (int*)alloc((size_t)(NT_ROWS + 1) * 4);
    int*   slot   = (int*)alloc((size_t)(E + P) * 4);
    int*   bsum   = (int*)alloc((size_t)nb * 4);
    int2*  cn     = (int2*)alloc((size_t)EP_MAX * 8);
    ushort_t* Wp  = (ushort_t*)alloc((size_t)K_CHEB * 4 * 64 * 8 * 2);
    ushort_t* xh  = (ushort_t*)alloc((size_t)B_SZ * NS32 * 2);
    ushort_t* hA  = (ushort_t*)alloc((size_t)B_SZ * NS32 * 2);
    ushort_t* hB  = (ushort_t*)alloc((size_t)B_SZ * NS32 * 2);
    ushort_t* hC  = (ushort_t*)alloc((size_t)B_SZ * NS32 * 2);
    ushort_t* z   = (ushort_t*)alloc((size_t)B_SZ * ZH * 2);

    hipMemsetAsync(deg, 0, (size_t)NT_ROWS * 4, stream);
    hipMemsetAsync(cn, 0, (size_t)EP_MAX * 8, stream);  // pad entries -> col 0, norm 0.0

    // combined CSR build (single atomic pass; atomicAdd return = slot)
    deg_slot_kernel<<<(E + P + 255) / 256, 256, 0, stream>>>(row, prow, deg, slot, E, P);
    disdegp_kernel<<<nb, 256, 0, stream>>>(deg, dis, degp);
    block_sum_kernel<<<nb, 256, 0, stream>>>(degp, bsum, NT_ROWS);
    scan_bsum_kernel<<<1, 64, 0, stream>>>(bsum, nb, rowptr, NT_ROWS);
    rowptr_kernel<<<nb, 256, 0, stream>>>(degp, bsum, rowptr, NT_ROWS);
    place_all_kernel<<<(E + P + 255) / 256, 256, 0, stream>>>(row, col, prow, pcol, pval, dis,
                                                              rowptr, slot, cn, E, P);
    // W pack + x cast
    packW_kernel<<<(K_CHEB * 4 * 64 * 8 + 255) / 256, 256, 0, stream>>>(W, Wp);
    int n2 = (int)(B_SZ * NS32 / 2);
    cast_h_kernel<<<(n2 + 255) / 256, 256, 0, stream>>>(x, (unsigned int*)xh, n2);

    int prop_blocks = ((N_NODES + 63) / 64) * B_SZ;  // 782 * 4 = 3128
    int gemm_blocks = (B_SZ * N_NODES) / 64;         // 3125

    // T1 = prop(x); T2 = 2*prop(T1) - x
    prop_kernel<<<prop_blocks, 256, 0, stream>>>(xh, nullptr, hA, rowptr, cn, 1.0f);
    prop_kernel<<<prop_blocks, 256, 0, stream>>>(hA, xh, hB, rowptr, cn, 2.0f);
    // z = [x,T1,T2] @ W[0:3] + bias
    gemm_mfma_kernel<<<gemm_blocks, 256, 0, stream>>>(xh, hA, hB, Wp, bias, z, 0);
    // T3, T4, T5
    prop_kernel<<<prop_blocks, 256, 0, stream>>>(hB, hA, hC, rowptr, cn, 2.0f);
    prop_kernel<<<prop_blocks, 256, 0, stream>>>(hC, hB, hA, rowptr, cn, 2.0f);
    prop_kernel<<<prop_blocks, 256, 0, stream>>>(hA, hC, hB, rowptr, cn, 2.0f);
    // z = ELU(z + [T3,T4,T5] @ W[3:6])
    gemm_mfma_kernel<<<gemm_blocks, 256, 0, stream>>>(hC, hA, hB, Wp + 3 * 4 * 64 * 8,
                                                      bias, z, 1);
    // pool
    pool_csr_kernel<<<(M_POOL + 7) / 8, 256, 0, stream>>>(z, rowptr, cn, (float*)d_out);
}

// Round 12
// 289.038 us; speedup vs baseline: 2.0528x; 1.0686x over previous
//
#include <hip/hip_runtime.h>
#include <hip/hip_fp16.h>
#include <cstdint>

#define N_NODES 50000
#define B_SZ 4
#define C_IN 32
#define C_OUT 64
#define K_CHEB 6
#define M_POOL 12500
#define NT_ROWS (N_NODES + M_POOL)
#define NS32 ((size_t)N_NODES * C_IN)
#define ZH ((size_t)N_NODES * C_OUT)   // z elements per batch (fp16)

typedef _Float16 f16x8 __attribute__((ext_vector_type(8)));
typedef float f32x4 __attribute__((ext_vector_type(4)));
typedef unsigned short ushort_t;

__device__ __forceinline__ unsigned short f2h(float f) {
    union { _Float16 h; unsigned short u; } v;
    v.h = (_Float16)f;
    return v.u;
}

__device__ __forceinline__ float h2f(unsigned short u) {
    union { unsigned short u; _Float16 h; } v;
    v.u = u;
    return (float)v.h;
}

__device__ __forceinline__ __half2 u2h2(unsigned u) { return __builtin_bit_cast(__half2, u); }
__device__ __forceinline__ unsigned h22u(__half2 h) { return __builtin_bit_cast(unsigned, h); }

// ---------------- Combined CSR build (rows 0..N-1 = graph, N..N+M-1 = pool) ----------------
__global__ void deg_slot_kernel(const int* __restrict__ row, const int* __restrict__ prow,
                                int* __restrict__ deg, int* __restrict__ slot, int E, int P) {
    int e = blockIdx.x * blockDim.x + threadIdx.x;
    if (e < E) slot[e] = atomicAdd(&deg[row[e]], 1);
    else if (e < E + P) slot[e] = atomicAdd(&deg[N_NODES + prow[e - E]], 1);
}

// dis for graph rows; padded degree: graph rows pad to multiple of 4, pool rows unpadded
__global__ void disdegp_kernel(const int* __restrict__ deg, float* __restrict__ dis,
                               int* __restrict__ degp) {
    int i = blockIdx.x * blockDim.x + threadIdx.x;
    if (i < N_NODES) {
        int d = deg[i];
        dis[i] = d > 0 ? rsqrtf((float)d) : 0.f;
        degp[i] = (d + 3) & ~3;
    } else if (i < NT_ROWS) {
        degp[i] = deg[i];
    }
}

__global__ void block_sum_kernel(const int* __restrict__ degp, int* __restrict__ bsum, int N) {
    __shared__ int sm[256];
    int i = blockIdx.x * 256 + threadIdx.x;
    sm[threadIdx.x] = (i < N) ? degp[i] : 0;
    __syncthreads();
    for (int s = 128; s > 0; s >>= 1) {
        if (threadIdx.x < s) sm[threadIdx.x] += sm[threadIdx.x + s];
        __syncthreads();
    }
    if (threadIdx.x == 0) bsum[blockIdx.x] = sm[0];
}

__global__ void scan_bsum_kernel(int* bsum, int nb, int* rowptr, int N) {
    if (blockIdx.x == 0 && threadIdx.x == 0) {
        int run = 0;
        for (int i = 0; i < nb; i++) { int v = bsum[i]; bsum[i] = run; run += v; }
        rowptr[N] = run;
    }
}

__global__ void rowptr_kernel(const int* __restrict__ degp, const int* __restrict__ bsum,
                              int* __restrict__ rowptr, int N) {
    __shared__ int sm[256];
    int i = blockIdx.x * 256 + threadIdx.x;
    sm[threadIdx.x] = (i < N) ? degp[i] : 0;
    __syncthreads();
    if (threadIdx.x == 0) {
        int run = bsum[blockIdx.x];
        for (int t = 0; t < 256; t++) { int v = sm[t]; sm[t] = run; run += v; }
    }
    __syncthreads();
    if (i < N) rowptr[i] = sm[threadIdx.x];
}

// zero only the pad slots of graph rows (replaces the 8 MB cn memset: 40 us -> ~5 us)
__global__ void pad_fill_kernel(const int* __restrict__ deg, const int* __restrict__ rowptr,
                                int2* __restrict__ cn) {
    int r = blockIdx.x * blockDim.x + threadIdx.x;
    if (r >= N_NODES) return;
    int p = rowptr[r] + deg[r];
    int p1 = rowptr[r + 1];
    for (; p < p1; ++p) cn[p] = make_int2(0, 0);
}

// atomic-free placement. Graph rows: cn.y = packed half2(norm,norm). Pool rows: cn.y = f32 bits.
__global__ void place_all_kernel(const int* __restrict__ row, const int* __restrict__ col,
                                 const int* __restrict__ prow, const int* __restrict__ pcol,
                                 const float* __restrict__ pval, const float* __restrict__ dis,
                                 const int* __restrict__ rowptr, const int* __restrict__ slot,
                                 int2* __restrict__ cn, int E, int P) {
    int e = blockIdx.x * blockDim.x + threadIdx.x;
    if (e < E) {
        int r = row[e], c = col[e];
        float nm = -dis[r] * dis[c];
        unsigned h = f2h(nm);
        cn[rowptr[r] + slot[e]] = make_int2(c, (int)(h | (h << 16)));
    } else if (e < E + P) {
        int i = e - E;
        int r = N_NODES + prow[i];
        cn[rowptr[r] + slot[e]] = make_int2(pcol[i], __float_as_int(pval[i]));
    }
}

// ---------------- fp32 -> fp16 cast ----------------
__global__ void cast_h_kernel(const float* __restrict__ in, unsigned int* __restrict__ out,
                              int n2) {
    int i = blockIdx.x * 256 + threadIdx.x;
    if (i < n2) {
        unsigned a = f2h(in[2 * i]), b = f2h(in[2 * i + 1]);
        out[i] = a | (b << 16);
    }
}

// ---------------- Chebyshev propagation (v11 structure, unchanged) ----------------
__global__ void prop_kernel(const ushort_t* __restrict__ hf, const ushort_t* __restrict__ p2f,
                            ushort_t* __restrict__ outf,
                            const int* __restrict__ rowptr, const int2* __restrict__ cn,
                            float alpha) {
    int bid = blockIdx.x;
    int b = bid & 3;
    int grp = bid >> 2;            // [0, 782)
    int lr = threadIdx.x >> 2;     // 0..63
    int cs = threadIdx.x & 3;      // channel oct: channels 8cs .. 8cs+7
    int r = grp * 64 + lr;
    if (r >= N_NODES) return;
    const char* hb = (const char*)hf + (size_t)b * NS32 * 2;
    unsigned coff = (unsigned)cs * 16u;
    int p0 = rowptr[r], p1 = rowptr[r + 1];
    __half2 a0 = __float2half2_rn(0.f), a1 = a0, a2 = a0, a3 = a0;
    if (p0 < p1) {
        int2 ea[4];
#pragma unroll
        for (int i = 0; i < 4; i++) ea[i] = cn[p0 + i];
        for (int p = p0 + 4; p < p1; p += 4) {
            uint4 v[4];
#pragma unroll
            for (int i = 0; i < 4; i++)
                v[i] = *(const uint4*)(hb + (((unsigned)ea[i].x << 6) + coff));
            int2 eb[4];
#pragma unroll
            for (int i = 0; i < 4; i++) eb[i] = cn[p + i];
#pragma unroll
            for (int i = 0; i < 4; i++) {
                __half2 n2 = u2h2((unsigned)ea[i].y);
                a0 = __hfma2(u2h2(v[i].x), n2, a0);
                a1 = __hfma2(u2h2(v[i].y), n2, a1);
                a2 = __hfma2(u2h2(v[i].z), n2, a2);
                a3 = __hfma2(u2h2(v[i].w), n2, a3);
            }
#pragma unroll
            for (int i = 0; i < 4; i++) ea[i] = eb[i];
        }
        uint4 v[4];
#pragma unroll
        for (int i = 0; i < 4; i++)
            v[i] = *(const uint4*)(hb + (((unsigned)ea[i].x << 6) + coff));
#pragma unroll
        for (int i = 0; i < 4; i++) {
            __half2 n2 = u2h2((unsigned)ea[i].y);
            a0 = __hfma2(u2h2(v[i].x), n2, a0);
            a1 = __hfma2(u2h2(v[i].y), n2, a1);
            a2 = __hfma2(u2h2(v[i].z), n2, a2);
            a3 = __hfma2(u2h2(v[i].w), n2, a3);
        }
    }
    unsigned ooff = ((unsigned)r << 6) + coff;
    uint4 o;
    if (p2f) {
        __half2 al2 = __float2half2_rn(alpha);
        uint4 pv = *(const uint4*)((const char*)p2f + (size_t)b * NS32 * 2 + ooff);
        o.x = h22u(__hfma2(a0, al2, __hneg2(u2h2(pv.x))));
        o.y = h22u(__hfma2(a1, al2, __hneg2(u2h2(pv.y))));
        o.z = h22u(__hfma2(a2, al2, __hneg2(u2h2(pv.z))));
        o.w = h22u(__hfma2(a3, al2, __hneg2(u2h2(pv.w))));
    } else {
        o.x = h22u(a0); o.y = h22u(a1); o.z = h22u(a2); o.w = h22u(a3);
    }
    *(uint4*)((char*)outf + (size_t)b * NS32 * 2 + ooff) = o;
}

// ---------------- W pack: [s][t][lane][j] fp16 fragment order ----------------
__global__ void packW_kernel(const float* __restrict__ W, ushort_t* __restrict__ Wp) {
    int i = blockIdx.x * 256 + threadIdx.x;
    if (i >= K_CHEB * 4 * 64 * 8) return;
    int j = i & 7;
    int lane = (i >> 3) & 63;
    int t = (i >> 9) & 3;
    int s = i >> 11;
    int k = (lane >> 4) * 8 + j;
    int col = t * 16 + (lane & 15);
    Wp[i] = f2h(W[((size_t)s * C_IN + k) * C_OUT + col]);
}

// ---------------- Single fused 6-source MFMA GEMM + bias + ELU -> fp16 z ----------------
__global__ void gemm_mfma_kernel(const ushort_t* __restrict__ T0, const ushort_t* __restrict__ T1,
                                 const ushort_t* __restrict__ T2, const ushort_t* __restrict__ T3,
                                 const ushort_t* __restrict__ T4, const ushort_t* __restrict__ T5,
                                 const ushort_t* __restrict__ Wp,
                                 const float* __restrict__ bias, ushort_t* __restrict__ z) {
    int lane = threadIdx.x & 63;
    int wave = (blockIdx.x << 2) + (threadIdx.x >> 6);
    int r0 = wave << 4;
    int ga = r0 + (lane & 15);
    int koff = (lane >> 4) * 8;
    const ushort_t* Ts[6] = {T0, T1, T2, T3, T4, T5};

    f16x8 afr[6];
#pragma unroll
    for (int s = 0; s < 6; s++)
        afr[s] = *(const f16x8*)(Ts[s] + (size_t)ga * C_IN + koff);

    int orow = r0 + ((lane >> 4) << 2);
#pragma unroll
    for (int t = 0; t < 4; t++) {
        f32x4 acc = {0.f, 0.f, 0.f, 0.f};
#pragma unroll
        for (int s = 0; s < 6; s++) {
            f16x8 bfr = *(const f16x8*)(Wp + ((s * 4 + t) * 64 + lane) * 8);
            acc = __builtin_amdgcn_mfma_f32_16x16x32_f16(afr[s], bfr, acc, 0, 0, 0);
        }
        int col = (t << 4) + (lane & 15);
        float bv = bias[col];
#pragma unroll
        for (int rg = 0; rg < 4; rg++) {
            float v = acc[rg] + bv;
            z[(size_t)(orow + rg) * C_OUT + col] = f2h(v > 0.f ? v : (expf(v) - 1.f));
        }
    }
}

// ---------------- Pool: deterministic CSR gather-reduce (fp16 z, combined rowptr) ----------
__global__ void pool_csr_kernel(const ushort_t* __restrict__ z, const int* __restrict__ rowptr,
                                const int2* __restrict__ cn, float* __restrict__ out) {
    int r = blockIdx.x * 8 + (threadIdx.x >> 5);
    int c2 = threadIdx.x & 31;   // channels 2c2, 2c2+1
    if (r >= M_POOL) return;
    const char* zb = (const char*)z;
    unsigned coff = (unsigned)c2 << 2;
    float s00 = 0.f, s01 = 0.f, s10 = 0.f, s11 = 0.f;
    float s20 = 0.f, s21 = 0.f, s30 = 0.f, s31 = 0.f;
    int p0 = rowptr[N_NODES + r], p1 = rowptr[N_NODES + r + 1];
    for (int p = p0; p < p1; ++p) {
        int2 e = cn[p];
        float v = __int_as_float(e.y);
        unsigned off = ((unsigned)e.x << 7) + coff;  // z row = 128B
        unsigned u0 = *(const unsigned*)(zb + off);
        unsigned u1 = *(const unsigned*)(zb + ZH * 2 + off);
        unsigned u2 = *(const unsigned*)(zb + 2 * ZH * 2 + off);
        unsigned u3 = *(const unsigned*)(zb + 3 * ZH * 2 + off);
        s00 += h2f((ushort_t)u0) * v; s01 += h2f((ushort_t)(u0 >> 16)) * v;
        s10 += h2f((ushort_t)u1) * v; s11 += h2f((ushort_t)(u1 >> 16)) * v;
        s20 += h2f((ushort_t)u2) * v; s21 += h2f((ushort_t)(u2 >> 16)) * v;
        s30 += h2f((ushort_t)u3) * v; s31 += h2f((ushort_t)(u3 >> 16)) * v;
    }
    size_t idx = (size_t)r * C_OUT + 2 * c2;
    size_t bs = (size_t)M_POOL * C_OUT;
    *(float2*)&out[idx]          = make_float2(s00, s01);
    *(float2*)&out[idx + bs]     = make_float2(s10, s11);
    *(float2*)&out[idx + 2 * bs] = make_float2(s20, s21);
    *(float2*)&out[idx + 3 * bs] = make_float2(s30, s31);
}

extern "C" void kernel_launch(void* const* d_in, const int* in_sizes, int n_in,
                              void* d_out, int out_size, void* d_ws, size_t ws_size,
                              hipStream_t stream) {
    const float* x    = (const float*)d_in[0];
    const int*   ei   = (const int*)d_in[1];
    const int*   prow = (const int*)d_in[2];
    const int*   pcol = (const int*)d_in[3];
    const float* pval = (const float*)d_in[4];
    const float* W    = (const float*)d_in[5];
    const float* bias = (const float*)d_in[6];
    const int E = in_sizes[1] / 2;
    const int P = in_sizes[2];
    const int* row = ei;
    const int* col = ei + E;
    const int EP_MAX = E + 3 * N_NODES + P;  // 4-padded CSR upper bound

    char* ws = (char*)d_ws;
    size_t o = 0;
    auto alloc = [&](size_t bytes) -> char* {
        char* p = ws + o;
        o += (bytes + 255) & ~(size_t)255;
        return p;
    };
    int nb = (NT_ROWS + 255) / 256;
    int*   deg    = (int*)alloc((size_t)NT_ROWS * 4);
    int*   degp   = (int*)alloc((size_t)NT_ROWS * 4);
    float* dis    = (float*)alloc((size_t)N_NODES * 4);
    int*   rowptr = (int*)alloc((size_t)(NT_ROWS + 1) * 4);
    int*   slot   = (int*)alloc((size_t)(E + P) * 4);
    int*   bsum   = (int*)alloc((size_t)nb * 4);
    int2*  cn     = (int2*)alloc((size_t)EP_MAX * 8);
    ushort_t* Wp  = (ushort_t*)alloc((size_t)K_CHEB * 4 * 64 * 8 * 2);
    ushort_t* xh  = (ushort_t*)alloc((size_t)B_SZ * NS32 * 2);
    ushort_t* hA  = (ushort_t*)alloc((size_t)B_SZ * NS32 * 2);  // T1
    ushort_t* hB  = (ushort_t*)alloc((size_t)B_SZ * NS32 * 2);  // T2
    ushort_t* hC  = (ushort_t*)alloc((size_t)B_SZ * NS32 * 2);  // T3
    ushort_t* hD  = (ushort_t*)alloc((size_t)B_SZ * NS32 * 2);  // T4
    ushort_t* hE  = (ushort_t*)alloc((size_t)B_SZ * NS32 * 2);  // T5
    ushort_t* z   = (ushort_t*)alloc((size_t)B_SZ * ZH * 2);

    hipMemsetAsync(deg, 0, (size_t)NT_ROWS * 4, stream);

    // combined CSR build (single atomic pass; atomicAdd return = slot)
    deg_slot_kernel<<<(E + P + 255) / 256, 256, 0, stream>>>(row, prow, deg, slot, E, P);
    disdegp_kernel<<<nb, 256, 0, stream>>>(deg, dis, degp);
    block_sum_kernel<<<nb, 256, 0, stream>>>(degp, bsum, NT_ROWS);
    scan_bsum_kernel<<<1, 64, 0, stream>>>(bsum, nb, rowptr, NT_ROWS);
    rowptr_kernel<<<nb, 256, 0, stream>>>(degp, bsum, rowptr, NT_ROWS);
    pad_fill_kernel<<<(N_NODES + 255) / 256, 256, 0, stream>>>(deg, rowptr, cn);
    place_all_kernel<<<(E + P + 255) / 256, 256, 0, stream>>>(row, col, prow, pcol, pval, dis,
                                                              rowptr, slot, cn, E, P);
    // W pack + x cast
    packW_kernel<<<(K_CHEB * 4 * 64 * 8 + 255) / 256, 256, 0, stream>>>(W, Wp);
    int n2 = (int)(B_SZ * NS32 / 2);
    cast_h_kernel<<<(n2 + 255) / 256, 256, 0, stream>>>(x, (unsigned int*)xh, n2);

    int prop_blocks = ((N_NODES + 63) / 64) * B_SZ;  // 782 * 4 = 3128
    int gemm_blocks = (B_SZ * N_NODES) / 64;         // 3125

    // Chebyshev chain: T1..T5 all kept
    prop_kernel<<<prop_blocks, 256, 0, stream>>>(xh, nullptr, hA, rowptr, cn, 1.0f);
    prop_kernel<<<prop_blocks, 256, 0, stream>>>(hA, xh, hB, rowptr, cn, 2.0f);
    prop_kernel<<<prop_blocks, 256, 0, stream>>>(hB, hA, hC, rowptr, cn, 2.0f);
    prop_kernel<<<prop_blocks, 256, 0, stream>>>(hC, hB, hD, rowptr, cn, 2.0f);
    prop_kernel<<<prop_blocks, 256, 0, stream>>>(hD, hC, hE, rowptr, cn, 2.0f);
    // z = ELU([x,T1..T5] @ W + bias), single pass
    gemm_mfma_kernel<<<gemm_blocks, 256, 0, stream>>>(xh, hA, hB, hC, hD, hE, Wp, bias, z);
    // pool
    pool_csr_kernel<<<(M_POOL + 7) / 8, 256, 0, stream>>>(z, rowptr, cn, (float*)d_out);
}

// Round 13
// 269.663 us; speedup vs baseline: 2.2003x; 1.0718x over previous
//
#include <hip/hip_runtime.h>
#include <hip/hip_fp16.h>
#include <cstdint>

#define N_NODES 50000
#define B_SZ 4
#define C_IN 32
#define C_OUT 64
#define K_CHEB 6
#define M_POOL 12500
#define NT_ROWS (N_NODES + M_POOL)
#define NS32 ((size_t)N_NODES * C_IN)
#define ZH ((size_t)N_NODES * C_OUT)   // z elements per batch (fp16)
#define CN_CAP 2048                    // LDS-staged cn entries per block (16 KB)

typedef _Float16 f16x8 __attribute__((ext_vector_type(8)));
typedef float f32x4 __attribute__((ext_vector_type(4)));
typedef unsigned short ushort_t;

__device__ __forceinline__ unsigned short f2h(float f) {
    union { _Float16 h; unsigned short u; } v;
    v.h = (_Float16)f;
    return v.u;
}

__device__ __forceinline__ float h2f(unsigned short u) {
    union { unsigned short u; _Float16 h; } v;
    v.u = u;
    return (float)v.h;
}

__device__ __forceinline__ __half2 u2h2(unsigned u) { return __builtin_bit_cast(__half2, u); }
__device__ __forceinline__ unsigned h22u(__half2 h) { return __builtin_bit_cast(unsigned, h); }

// ---------------- tiny zero kernel (hipMemsetAsync small-fill costs ~40 us!) ----------------
__global__ void zero_deg_kernel(int* __restrict__ deg) {
    int i = blockIdx.x * 256 + threadIdx.x;
    if (i < NT_ROWS) deg[i] = 0;
}

// ---------------- Combined CSR build (rows 0..N-1 = graph, N..N+M-1 = pool) ----------------
// 4 edges/thread: 4 independent atomics in flight per lane
__global__ void deg_slot_kernel(const int* __restrict__ row, const int* __restrict__ prow,
                                int* __restrict__ deg, int* __restrict__ slot, int E, int P) {
    int base = (blockIdx.x * blockDim.x + threadIdx.x) * 4;
#pragma unroll
    for (int k = 0; k < 4; k++) {
        int e = base + k;
        if (e < E) slot[e] = atomicAdd(&deg[row[e]], 1);
        else if (e < E + P) slot[e] = atomicAdd(&deg[N_NODES + prow[e - E]], 1);
    }
}

// dis for graph rows; padded degree: graph rows pad to multiple of 4, pool rows unpadded
__global__ void disdegp_kernel(const int* __restrict__ deg, float* __restrict__ dis,
                               int* __restrict__ degp) {
    int i = blockIdx.x * blockDim.x + threadIdx.x;
    if (i < N_NODES) {
        int d = deg[i];
        dis[i] = d > 0 ? rsqrtf((float)d) : 0.f;
        degp[i] = (d + 3) & ~3;
    } else if (i < NT_ROWS) {
        degp[i] = deg[i];
    }
}

__global__ void block_sum_kernel(const int* __restrict__ degp, int* __restrict__ bsum, int N) {
    __shared__ int sm[256];
    int i = blockIdx.x * 256 + threadIdx.x;
    sm[threadIdx.x] = (i < N) ? degp[i] : 0;
    __syncthreads();
    for (int s = 128; s > 0; s >>= 1) {
        if (threadIdx.x < s) sm[threadIdx.x] += sm[threadIdx.x + s];
        __syncthreads();
    }
    if (threadIdx.x == 0) bsum[blockIdx.x] = sm[0];
}

__global__ void scan_bsum_kernel(int* bsum, int nb, int* rowptr, int N) {
    if (blockIdx.x == 0 && threadIdx.x == 0) {
        int run = 0;
        for (int i = 0; i < nb; i++) { int v = bsum[i]; bsum[i] = run; run += v; }
        rowptr[N] = run;
    }
}

__global__ void rowptr_kernel(const int* __restrict__ degp, const int* __restrict__ bsum,
                              int* __restrict__ rowptr, int N) {
    __shared__ int sm[256];
    int i = blockIdx.x * 256 + threadIdx.x;
    sm[threadIdx.x] = (i < N) ? degp[i] : 0;
    __syncthreads();
    if (threadIdx.x == 0) {
        int run = bsum[blockIdx.x];
        for (int t = 0; t < 256; t++) { int v = sm[t]; sm[t] = run; run += v; }
    }
    __syncthreads();
    if (i < N) rowptr[i] = sm[threadIdx.x];
}

// zero only the pad slots of graph rows
__global__ void pad_fill_kernel(const int* __restrict__ deg, const int* __restrict__ rowptr,
                                int2* __restrict__ cn) {
    int r = blockIdx.x * blockDim.x + threadIdx.x;
    if (r >= N_NODES) return;
    int p = rowptr[r] + deg[r];
    int p1 = rowptr[r + 1];
    for (; p < p1; ++p) cn[p] = make_int2(0, 0);
}

// atomic-free placement. Graph rows: cn.y = packed half2(norm,norm). Pool rows: cn.y = f32 bits.
__global__ void place_all_kernel(const int* __restrict__ row, const int* __restrict__ col,
                                 const int* __restrict__ prow, const int* __restrict__ pcol,
                                 const float* __restrict__ pval, const float* __restrict__ dis,
                                 const int* __restrict__ rowptr, const int* __restrict__ slot,
                                 int2* __restrict__ cn, int E, int P) {
    int e = blockIdx.x * blockDim.x + threadIdx.x;
    if (e < E) {
        int r = row[e], c = col[e];
        float nm = -dis[r] * dis[c];
        unsigned h = f2h(nm);
        cn[rowptr[r] + slot[e]] = make_int2(c, (int)(h | (h << 16)));
    } else if (e < E + P) {
        int i = e - E;
        int r = N_NODES + prow[i];
        cn[rowptr[r] + slot[e]] = make_int2(pcol[i], __float_as_int(pval[i]));
    }
}

// ---------------- fp32 -> fp16 cast ----------------
__global__ void cast_h_kernel(const float* __restrict__ in, unsigned int* __restrict__ out,
                              int n2) {
    int i = blockIdx.x * 256 + threadIdx.x;
    if (i < n2) {
        unsigned a = f2h(in[2 * i]), b = f2h(in[2 * i + 1]);
        out[i] = a | (b << 16);
    }
}

// ---------------- Chebyshev propagation v12: LDS-staged cn ----------------
// Block = 64 rows x ONE batch (bid&3 -> per-XCD 3.2 MB slice). The block's cn range is
// contiguous: stage it into LDS cooperatively (coalesced), then 4 lanes/row read cn
// via LDS broadcast (same addr -> conflict-free). Feature gathers are the only
// global loads in the loop. Fallback to global cn if range > CN_CAP (never on this data).
__global__ void prop_kernel(const ushort_t* __restrict__ hf, const ushort_t* __restrict__ p2f,
                            ushort_t* __restrict__ outf,
                            const int* __restrict__ rowptr, const int2* __restrict__ cn,
                            float alpha) {
    __shared__ int2 lcn[CN_CAP];
    int bid = blockIdx.x;
    int b = bid & 3;
    int grp = bid >> 2;            // [0, 782)
    int r0 = grp * 64;
    int rend = r0 + 64 > N_NODES ? N_NODES : r0 + 64;
    int pbase = rowptr[r0];
    int pend = rowptr[rend];
    int cnt = pend - pbase;
    bool use_lds = (cnt <= CN_CAP);
    if (use_lds) {
        for (int i = threadIdx.x; i < cnt; i += 256) lcn[i] = cn[pbase + i];
    }
    __syncthreads();

    int lr = threadIdx.x >> 2;     // 0..63
    int cs = threadIdx.x & 3;      // channel oct
    int r = r0 + lr;
    if (r >= N_NODES) return;
    const char* hb = (const char*)hf + (size_t)b * NS32 * 2;
    unsigned coff = (unsigned)cs * 16u;
    __half2 a0 = __float2half2_rn(0.f), a1 = a0, a2 = a0, a3 = a0;

    if (use_lds) {
        int p0 = rowptr[r] - pbase, p1 = rowptr[r + 1] - pbase;
        for (int p = p0; p < p1; p += 4) {
            int2 e0 = lcn[p], e1 = lcn[p + 1], e2 = lcn[p + 2], e3 = lcn[p + 3];
            uint4 v0 = *(const uint4*)(hb + (((unsigned)e0.x << 6) + coff));
            uint4 v1 = *(const uint4*)(hb + (((unsigned)e1.x << 6) + coff));
            uint4 v2 = *(const uint4*)(hb + (((unsigned)e2.x << 6) + coff));
            uint4 v3 = *(const uint4*)(hb + (((unsigned)e3.x << 6) + coff));
            __half2 n0 = u2h2((unsigned)e0.y), n1 = u2h2((unsigned)e1.y);
            __half2 n2 = u2h2((unsigned)e2.y), n3 = u2h2((unsigned)e3.y);
            a0 = __hfma2(u2h2(v0.x), n0, a0); a1 = __hfma2(u2h2(v0.y), n0, a1);
            a2 = __hfma2(u2h2(v0.z), n0, a2); a3 = __hfma2(u2h2(v0.w), n0, a3);
            a0 = __hfma2(u2h2(v1.x), n1, a0); a1 = __hfma2(u2h2(v1.y), n1, a1);
            a2 = __hfma2(u2h2(v1.z), n1, a2); a3 = __hfma2(u2h2(v1.w), n1, a3);
            a0 = __hfma2(u2h2(v2.x), n2, a0); a1 = __hfma2(u2h2(v2.y), n2, a1);
            a2 = __hfma2(u2h2(v2.z), n2, a2); a3 = __hfma2(u2h2(v2.w), n2, a3);
            a0 = __hfma2(u2h2(v3.x), n3, a0); a1 = __hfma2(u2h2(v3.y), n3, a1);
            a2 = __hfma2(u2h2(v3.z), n3, a2); a3 = __hfma2(u2h2(v3.w), n3, a3);
        }
    } else {
        int p0 = rowptr[r], p1 = rowptr[r + 1];
        for (int p = p0; p < p1; p += 4) {
            int2 e0 = cn[p], e1 = cn[p + 1], e2 = cn[p + 2], e3 = cn[p + 3];
            uint4 v0 = *(const uint4*)(hb + (((unsigned)e0.x << 6) + coff));
            uint4 v1 = *(const uint4*)(hb + (((unsigned)e1.x << 6) + coff));
            uint4 v2 = *(const uint4*)(hb + (((unsigned)e2.x << 6) + coff));
            uint4 v3 = *(const uint4*)(hb + (((unsigned)e3.x << 6) + coff));
            __half2 n0 = u2h2((unsigned)e0.y), n1 = u2h2((unsigned)e1.y);
            __half2 n2 = u2h2((unsigned)e2.y), n3 = u2h2((unsigned)e3.y);
            a0 = __hfma2(u2h2(v0.x), n0, a0); a1 = __hfma2(u2h2(v0.y), n0, a1);
            a2 = __hfma2(u2h2(v0.z), n0, a2); a3 = __hfma2(u2h2(v0.w), n0, a3);
            a0 = __hfma2(u2h2(v1.x), n1, a0); a1 = __hfma2(u2h2(v1.y), n1, a1);
            a2 = __hfma2(u2h2(v1.z), n1, a2); a3 = __hfma2(u2h2(v1.w), n1, a3);
            a0 = __hfma2(u2h2(v2.x), n2, a0); a1 = __hfma2(u2h2(v2.y), n2, a1);
            a2 = __hfma2(u2h2(v2.z), n2, a2); a3 = __hfma2(u2h2(v2.w), n2, a3);
            a0 = __hfma2(u2h2(v3.x), n3, a0); a1 = __hfma2(u2h2(v3.y), n3, a1);
            a2 = __hfma2(u2h2(v3.z), n3, a2); a3 = __hfma2(u2h2(v3.w), n3, a3);
        }
    }

    unsigned ooff = ((unsigned)r << 6) + coff;
    uint4 o;
    if (p2f) {
        __half2 al2 = __float2half2_rn(alpha);
        uint4 pv = *(const uint4*)((const char*)p2f + (size_t)b * NS32 * 2 + ooff);
        o.x = h22u(__hfma2(a0, al2, __hneg2(u2h2(pv.x))));
        o.y = h22u(__hfma2(a1, al2, __hneg2(u2h2(pv.y))));
        o.z = h22u(__hfma2(a2, al2, __hneg2(u2h2(pv.z))));
        o.w = h22u(__hfma2(a3, al2, __hneg2(u2h2(pv.w))));
    } else {
        o.x = h22u(a0); o.y = h22u(a1); o.z = h22u(a2); o.w = h22u(a3);
    }
    *(uint4*)((char*)outf + (size_t)b * NS32 * 2 + ooff) = o;
}

// ---------------- W pack: [s][t][lane][j] fp16 fragment order ----------------
__global__ void packW_kernel(const float* __restrict__ W, ushort_t* __restrict__ Wp) {
    int i = blockIdx.x * 256 + threadIdx.x;
    if (i >= K_CHEB * 4 * 64 * 8) return;
    int j = i & 7;
    int lane = (i >> 3) & 63;
    int t = (i >> 9) & 3;
    int s = i >> 11;
    int k = (lane >> 4) * 8 + j;
    int col = t * 16 + (lane & 15);
    Wp[i] = f2h(W[((size_t)s * C_IN + k) * C_OUT + col]);
}

// ---------------- Single fused 6-source MFMA GEMM + bias + ELU -> fp16 z ----------------
__global__ void gemm_mfma_kernel(const ushort_t* __restrict__ T0, const ushort_t* __restrict__ T1,
                                 const ushort_t* __restrict__ T2, const ushort_t* __restrict__ T3,
                                 const ushort_t* __restrict__ T4, const ushort_t* __restrict__ T5,
                                 const ushort_t* __restrict__ Wp,
                                 const float* __restrict__ bias, ushort_t* __restrict__ z) {
    int lane = threadIdx.x & 63;
    int wave = (blockIdx.x << 2) + (threadIdx.x >> 6);
    int r0 = wave << 4;
    int ga = r0 + (lane & 15);
    int koff = (lane >> 4) * 8;
    const ushort_t* Ts[6] = {T0, T1, T2, T3, T4, T5};

    f16x8 afr[6];
#pragma unroll
    for (int s = 0; s < 6; s++)
        afr[s] = *(const f16x8*)(Ts[s] + (size_t)ga * C_IN + koff);

    int orow = r0 + ((lane >> 4) << 2);
#pragma unroll
    for (int t = 0; t < 4; t++) {
        f32x4 acc = {0.f, 0.f, 0.f, 0.f};
#pragma unroll
        for (int s = 0; s < 6; s++) {
            f16x8 bfr = *(const f16x8*)(Wp + ((s * 4 + t) * 64 + lane) * 8);
            acc = __builtin_amdgcn_mfma_f32_16x16x32_f16(afr[s], bfr, acc, 0, 0, 0);
        }
        int col = (t << 4) + (lane & 15);
        float bv = bias[col];
#pragma unroll
        for (int rg = 0; rg < 4; rg++) {
            float v = acc[rg] + bv;
            z[(size_t)(orow + rg) * C_OUT + col] = f2h(v > 0.f ? v : (expf(v) - 1.f));
        }
    }
}

// ---------------- Pool: deterministic CSR gather-reduce (fp16 z, combined rowptr) ----------
__global__ void pool_csr_kernel(const ushort_t* __restrict__ z, const int* __restrict__ rowptr,
                                const int2* __restrict__ cn, float* __restrict__ out) {
    int r = blockIdx.x * 8 + (threadIdx.x >> 5);
    int c2 = threadIdx.x & 31;   // channels 2c2, 2c2+1
    if (r >= M_POOL) return;
    const char* zb = (const char*)z;
    unsigned coff = (unsigned)c2 << 2;
    float s00 = 0.f, s01 = 0.f, s10 = 0.f, s11 = 0.f;
    float s20 = 0.f, s21 = 0.f, s30 = 0.f, s31 = 0.f;
    int p0 = rowptr[N_NODES + r], p1 = rowptr[N_NODES + r + 1];
    for (int p = p0; p < p1; ++p) {
        int2 e = cn[p];
        float v = __int_as_float(e.y);
        unsigned off = ((unsigned)e.x << 7) + coff;  // z row = 128B
        unsigned u0 = *(const unsigned*)(zb + off);
        unsigned u1 = *(const unsigned*)(zb + ZH * 2 + off);
        unsigned u2 = *(const unsigned*)(zb + 2 * ZH * 2 + off);
        unsigned u3 = *(const unsigned*)(zb + 3 * ZH * 2 + off);
        s00 += h2f((ushort_t)u0) * v; s01 += h2f((ushort_t)(u0 >> 16)) * v;
        s10 += h2f((ushort_t)u1) * v; s11 += h2f((ushort_t)(u1 >> 16)) * v;
        s20 += h2f((ushort_t)u2) * v; s21 += h2f((ushort_t)(u2 >> 16)) * v;
        s30 += h2f((ushort_t)u3) * v; s31 += h2f((ushort_t)(u3 >> 16)) * v;
    }
    size_t idx = (size_t)r * C_OUT + 2 * c2;
    size_t bs = (size_t)M_POOL * C_OUT;
    *(float2*)&out[idx]          = make_float2(s00, s01);
    *(float2*)&out[idx + bs]     = make_float2(s10, s11);
    *(float2*)&out[idx + 2 * bs] = make_float2(s20, s21);
    *(float2*)&out[idx + 3 * bs] = make_float2(s30, s31);
}

extern "C" void kernel_launch(void* const* d_in, const int* in_sizes, int n_in,
                              void* d_out, int out_size, void* d_ws, size_t ws_size,
                              hipStream_t stream) {
    const float* x    = (const float*)d_in[0];
    const int*   ei   = (const int*)d_in[1];
    const int*   prow = (const int*)d_in[2];
    const int*   pcol = (const int*)d_in[3];
    const float* pval = (const float*)d_in[4];
    const float* W    = (const float*)d_in[5];
    const float* bias = (const float*)d_in[6];
    const int E = in_sizes[1] / 2;
    const int P = in_sizes[2];
    const int* row = ei;
    const int* col = ei + E;
    const int EP_MAX = E + 3 * N_NODES + P;  // 4-padded CSR upper bound

    char* ws = (char*)d_ws;
    size_t o = 0;
    auto alloc = [&](size_t bytes) -> char* {
        char* p = ws + o;
        o += (bytes + 255) & ~(size_t)255;
        return p;
    };
    int nb = (NT_ROWS + 255) / 256;
    int*   deg    = (int*)alloc((size_t)NT_ROWS * 4);
    int*   degp   = (int*)alloc((size_t)NT_ROWS * 4);
    float* dis    = (float*)alloc((size_t)N_NODES * 4);
    int*   rowptr = (int*)alloc((size_t)(NT_ROWS + 1) * 4);
    int*   slot   = (int*)alloc((size_t)(E + P) * 4);
    int*   bsum   = (int*)alloc((size_t)nb * 4);
    int2*  cn     = (int2*)alloc((size_t)EP_MAX * 8);
    ushort_t* Wp  = (ushort_t*)alloc((size_t)K_CHEB * 4 * 64 * 8 * 2);
    ushort_t* xh  = (ushort_t*)alloc((size_t)B_SZ * NS32 * 2);
    ushort_t* hA  = (ushort_t*)alloc((size_t)B_SZ * NS32 * 2);  // T1
    ushort_t* hB  = (ushort_t*)alloc((size_t)B_SZ * NS32 * 2);  // T2
    ushort_t* hC  = (ushort_t*)alloc((size_t)B_SZ * NS32 * 2);  // T3
    ushort_t* hD  = (ushort_t*)alloc((size_t)B_SZ * NS32 * 2);  // T4
    ushort_t* hE  = (ushort_t*)alloc((size_t)B_SZ * NS32 * 2);  // T5
    ushort_t* z   = (ushort_t*)alloc((size_t)B_SZ * ZH * 2);

    // combined CSR build
    zero_deg_kernel<<<nb, 256, 0, stream>>>(deg);
    deg_slot_kernel<<<(E + P + 1023) / 1024, 256, 0, stream>>>(row, prow, deg, slot, E, P);
    disdegp_kernel<<<nb, 256, 0, stream>>>(deg, dis, degp);
    block_sum_kernel<<<nb, 256, 0, stream>>>(degp, bsum, NT_ROWS);
    scan_bsum_kernel<<<1, 64, 0, stream>>>(bsum, nb, rowptr, NT_ROWS);
    rowptr_kernel<<<nb, 256, 0, stream>>>(degp, bsum, rowptr, NT_ROWS);
    pad_fill_kernel<<<(N_NODES + 255) / 256, 256, 0, stream>>>(deg, rowptr, cn);
    place_all_kernel<<<(E + P + 255) / 256, 256, 0, stream>>>(row, col, prow, pcol, pval, dis,
                                                              rowptr, slot, cn, E, P);
    // W pack + x cast
    packW_kernel<<<(K_CHEB * 4 * 64 * 8 + 255) / 256, 256, 0, stream>>>(W, Wp);
    int n2 = (int)(B_SZ * NS32 / 2);
    cast_h_kernel<<<(n2 + 255) / 256, 256, 0, stream>>>(x, (unsigned int*)xh, n2);

    int prop_blocks = ((N_NODES + 63) / 64) * B_SZ;  // 782 * 4 = 3128
    int gemm_blocks = (B_SZ * N_NODES) / 64;         // 3125

    // Chebyshev chain: T1..T5 all kept
    prop_kernel<<<prop_blocks, 256, 0, stream>>>(xh, nullptr, hA, rowptr, cn, 1.0f);
    prop_kernel<<<prop_blocks, 256, 0, stream>>>(hA, xh, hB, rowptr, cn, 2.0f);
    prop_kernel<<<prop_blocks, 256, 0, stream>>>(hB, hA, hC, rowptr, cn, 2.0f);
    prop_kernel<<<prop_blocks, 256, 0, stream>>>(hC, hB, hD, rowptr, cn, 2.0f);
    prop_kernel<<<prop_blocks, 256, 0, stream>>>(hD, hC, hE, rowptr, cn, 2.0f);
    // z = ELU([x,T1..T5] @ W + bias), single pass
    gemm_mfma_kernel<<<gemm_blocks, 256, 0, stream>>>(xh, hA, hB, hC, hD, hE, Wp, bias, z);
    // pool
    pool_csr_kernel<<<(M_POOL + 7) / 8, 256, 0, stream>>>(z, rowptr, cn, (float*)d_out);
}

// Round 14
// 255.555 us; speedup vs baseline: 2.3217x; 1.0552x over previous
//
#include <hip/hip_runtime.h>
#include <hip/hip_fp16.h>
#include <cstdint>

#define N_NODES 50000
#define B_SZ 4
#define C_IN 32
#define C_OUT 64
#define K_CHEB 6
#define M_POOL 12500
#define NT_ROWS (N_NODES + M_POOL)
#define NS32 ((size_t)N_NODES * C_IN)
#define ZH ((size_t)N_NODES * C_OUT)   // z elements per batch (fp16)
#define CN_CAP 2048                    // LDS-staged cn entries per block (16 KB)

typedef _Float16 f16x8 __attribute__((ext_vector_type(8)));
typedef float f32x4 __attribute__((ext_vector_type(4)));
typedef unsigned short ushort_t;

__device__ __forceinline__ unsigned short f2h(float f) {
    union { _Float16 h; unsigned short u; } v;
    v.h = (_Float16)f;
    return v.u;
}

__device__ __forceinline__ float h2f(unsigned short u) {
    union { unsigned short u; _Float16 h; } v;
    v.u = u;
    return (float)v.h;
}

__device__ __forceinline__ __half2 u2h2(unsigned u) { return __builtin_bit_cast(__half2, u); }
__device__ __forceinline__ unsigned h22u(__half2 h) { return __builtin_bit_cast(unsigned, h); }

// ---------------- tiny zero kernel (hipMemsetAsync small-fill costs ~40 us!) ----------------
__global__ void zero_deg_kernel(int* __restrict__ deg) {
    int i = blockIdx.x * 256 + threadIdx.x;
    if (i < NT_ROWS) deg[i] = 0;
}

// ---------------- Combined CSR build (rows 0..N-1 = graph, N..N+M-1 = pool) ----------------
__global__ void deg_slot_kernel(const int* __restrict__ row, const int* __restrict__ prow,
                                int* __restrict__ deg, int* __restrict__ slot, int E, int P) {
    int e = blockIdx.x * blockDim.x + threadIdx.x;
    if (e < E) slot[e] = atomicAdd(&deg[row[e]], 1);
    else if (e < E + P) slot[e] = atomicAdd(&deg[N_NODES + prow[e - E]], 1);
}

// dis for graph rows; padded degree: graph rows pad to multiple of 8, pool rows unpadded
__global__ void disdegp_kernel(const int* __restrict__ deg, float* __restrict__ dis,
                               int* __restrict__ degp) {
    int i = blockIdx.x * blockDim.x + threadIdx.x;
    if (i < N_NODES) {
        int d = deg[i];
        dis[i] = d > 0 ? rsqrtf((float)d) : 0.f;
        degp[i] = (d + 7) & ~7;
    } else if (i < NT_ROWS) {
        degp[i] = deg[i];
    }
}

__global__ void block_sum_kernel(const int* __restrict__ degp, int* __restrict__ bsum, int N) {
    __shared__ int sm[256];
    int i = blockIdx.x * 256 + threadIdx.x;
    sm[threadIdx.x] = (i < N) ? degp[i] : 0;
    __syncthreads();
    for (int s = 128; s > 0; s >>= 1) {
        if (threadIdx.x < s) sm[threadIdx.x] += sm[threadIdx.x + s];
        __syncthreads();
    }
    if (threadIdx.x == 0) bsum[blockIdx.x] = sm[0];
}

// parallel exclusive scan over nb (<=256) block sums, one block (replaces serial scan)
__global__ void scan_bsum_kernel(int* bsum, int nb, int* rowptr, int N) {
    __shared__ int sm[256];
    int t = threadIdx.x;
    int v = (t < nb) ? bsum[t] : 0;
    sm[t] = v;
    __syncthreads();
    for (int off = 1; off < 256; off <<= 1) {
        int u = (t >= off) ? sm[t - off] : 0;
        __syncthreads();
        sm[t] += u;
        __syncthreads();
    }
    if (t < nb) bsum[t] = sm[t] - v;   // exclusive
    if (t == 0) rowptr[N] = sm[255];   // grand total
}

__global__ void rowptr_kernel(const int* __restrict__ degp, const int* __restrict__ bsum,
                              int* __restrict__ rowptr, int N) {
    __shared__ int sm[256];
    int i = blockIdx.x * 256 + threadIdx.x;
    sm[threadIdx.x] = (i < N) ? degp[i] : 0;
    __syncthreads();
    if (threadIdx.x == 0) {
        int run = bsum[blockIdx.x];
        for (int t = 0; t < 256; t++) { int v = sm[t]; sm[t] = run; run += v; }
    }
    __syncthreads();
    if (i < N) rowptr[i] = sm[threadIdx.x];
}

// zero only the pad slots of graph rows
__global__ void pad_fill_kernel(const int* __restrict__ deg, const int* __restrict__ rowptr,
                                int2* __restrict__ cn) {
    int r = blockIdx.x * blockDim.x + threadIdx.x;
    if (r >= N_NODES) return;
    int p = rowptr[r] + deg[r];
    int p1 = rowptr[r + 1];
    for (; p < p1; ++p) cn[p] = make_int2(0, 0);
}

// atomic-free placement. Graph rows: cn.y = packed half2(norm,norm). Pool rows: cn.y = f32 bits.
__global__ void place_all_kernel(const int* __restrict__ row, const int* __restrict__ col,
                                 const int* __restrict__ prow, const int* __restrict__ pcol,
                                 const float* __restrict__ pval, const float* __restrict__ dis,
                                 const int* __restrict__ rowptr, const int* __restrict__ slot,
                                 int2* __restrict__ cn, int E, int P) {
    int e = blockIdx.x * blockDim.x + threadIdx.x;
    if (e < E) {
        int r = row[e], c = col[e];
        float nm = -dis[r] * dis[c];
        unsigned h = f2h(nm);
        cn[rowptr[r] + slot[e]] = make_int2(c, (int)(h | (h << 16)));
    } else if (e < E + P) {
        int i = e - E;
        int r = N_NODES + prow[i];
        cn[rowptr[r] + slot[e]] = make_int2(pcol[i], __float_as_int(pval[i]));
    }
}

// ---------------- fp32 -> fp16 cast ----------------
__global__ void cast_h_kernel(const float* __restrict__ in, unsigned int* __restrict__ out,
                              int n2) {
    int i = blockIdx.x * 256 + threadIdx.x;
    if (i < n2) {
        unsigned a = f2h(in[2 * i]), b = f2h(in[2 * i + 1]);
        out[i] = a | (b << 16);
    }
}

// ---------------- Chebyshev propagation v13: LDS cn + 8-deep gather pipeline ----------------
// Block = 64 rows x ONE batch (bid&3 -> per-XCD slice affinity). cn range staged in LDS;
// rows padded to x8 -> unconditional 8-wide iterations: 8 LDS cn reads, then 8 independent
// 16B feature gathers in flight, then 32 hfma2.
__global__ void prop_kernel(const ushort_t* __restrict__ hf, const ushort_t* __restrict__ p2f,
                            ushort_t* __restrict__ outf,
                            const int* __restrict__ rowptr, const int2* __restrict__ cn,
                            float alpha) {
    __shared__ int2 lcn[CN_CAP];
    int bid = blockIdx.x;
    int b = bid & 3;
    int grp = bid >> 2;            // [0, 782)
    int r0 = grp * 64;
    int rend = r0 + 64 > N_NODES ? N_NODES : r0 + 64;
    int pbase = rowptr[r0];
    int pend = rowptr[rend];
    int cnt = pend - pbase;
    bool use_lds = (cnt <= CN_CAP);
    if (use_lds) {
        for (int i = threadIdx.x; i < cnt; i += 256) lcn[i] = cn[pbase + i];
    }
    __syncthreads();

    int lr = threadIdx.x >> 2;     // 0..63
    int cs = threadIdx.x & 3;      // channel oct
    int r = r0 + lr;
    if (r >= N_NODES) return;
    const char* hb = (const char*)hf + (size_t)b * NS32 * 2;
    unsigned coff = (unsigned)cs * 16u;
    __half2 a0 = __float2half2_rn(0.f), a1 = a0, a2 = a0, a3 = a0;

    if (use_lds) {
        int p0 = rowptr[r] - pbase, p1 = rowptr[r + 1] - pbase;
        for (int p = p0; p < p1; p += 8) {
            int2 ea[8];
#pragma unroll
            for (int i = 0; i < 8; i++) ea[i] = lcn[p + i];
            uint4 v[8];
#pragma unroll
            for (int i = 0; i < 8; i++)
                v[i] = *(const uint4*)(hb + (((unsigned)ea[i].x << 6) + coff));
#pragma unroll
            for (int i = 0; i < 8; i++) {
                __half2 n = u2h2((unsigned)ea[i].y);
                a0 = __hfma2(u2h2(v[i].x), n, a0);
                a1 = __hfma2(u2h2(v[i].y), n, a1);
                a2 = __hfma2(u2h2(v[i].z), n, a2);
                a3 = __hfma2(u2h2(v[i].w), n, a3);
            }
        }
    } else {
        int p0 = rowptr[r], p1 = rowptr[r + 1];
        for (int p = p0; p < p1; p += 8) {
            int2 ea[8];
#pragma unroll
            for (int i = 0; i < 8; i++) ea[i] = cn[p + i];
            uint4 v[8];
#pragma unroll
            for (int i = 0; i < 8; i++)
                v[i] = *(const uint4*)(hb + (((unsigned)ea[i].x << 6) + coff));
#pragma unroll
            for (int i = 0; i < 8; i++) {
                __half2 n = u2h2((unsigned)ea[i].y);
                a0 = __hfma2(u2h2(v[i].x), n, a0);
                a1 = __hfma2(u2h2(v[i].y), n, a1);
                a2 = __hfma2(u2h2(v[i].z), n, a2);
                a3 = __hfma2(u2h2(v[i].w), n, a3);
            }
        }
    }

    unsigned ooff = ((unsigned)r << 6) + coff;
    uint4 o;
    if (p2f) {
        __half2 al2 = __float2half2_rn(alpha);
        uint4 pv = *(const uint4*)((const char*)p2f + (size_t)b * NS32 * 2 + ooff);
        o.x = h22u(__hfma2(a0, al2, __hneg2(u2h2(pv.x))));
        o.y = h22u(__hfma2(a1, al2, __hneg2(u2h2(pv.y))));
        o.z = h22u(__hfma2(a2, al2, __hneg2(u2h2(pv.z))));
        o.w = h22u(__hfma2(a3, al2, __hneg2(u2h2(pv.w))));
    } else {
        o.x = h22u(a0); o.y = h22u(a1); o.z = h22u(a2); o.w = h22u(a3);
    }
    *(uint4*)((char*)outf + (size_t)b * NS32 * 2 + ooff) = o;
}

// ---------------- W pack: [s][t][lane][j] fp16 fragment order ----------------
__global__ void packW_kernel(const float* __restrict__ W, ushort_t* __restrict__ Wp) {
    int i = blockIdx.x * 256 + threadIdx.x;
    if (i >= K_CHEB * 4 * 64 * 8) return;
    int j = i & 7;
    int lane = (i >> 3) & 63;
    int t = (i >> 9) & 3;
    int s = i >> 11;
    int k = (lane >> 4) * 8 + j;
    int col = t * 16 + (lane & 15);
    Wp[i] = f2h(W[((size_t)s * C_IN + k) * C_OUT + col]);
}

// ---------------- Single fused 6-source MFMA GEMM + bias + ELU -> fp16 z ----------------
__global__ void gemm_mfma_kernel(const ushort_t* __restrict__ T0, const ushort_t* __restrict__ T1,
                                 const ushort_t* __restrict__ T2, const ushort_t* __restrict__ T3,
                                 const ushort_t* __restrict__ T4, const ushort_t* __restrict__ T5,
                                 const ushort_t* __restrict__ Wp,
                                 const float* __restrict__ bias, ushort_t* __restrict__ z) {
    int lane = threadIdx.x & 63;
    int wave = (blockIdx.x << 2) + (threadIdx.x >> 6);
    int r0 = wave << 4;
    int ga = r0 + (lane & 15);
    int koff = (lane >> 4) * 8;
    const ushort_t* Ts[6] = {T0, T1, T2, T3, T4, T5};

    f16x8 afr[6];
#pragma unroll
    for (int s = 0; s < 6; s++)
        afr[s] = *(const f16x8*)(Ts[s] + (size_t)ga * C_IN + koff);

    int orow = r0 + ((lane >> 4) << 2);
#pragma unroll
    for (int t = 0; t < 4; t++) {
        f32x4 acc = {0.f, 0.f, 0.f, 0.f};
#pragma unroll
        for (int s = 0; s < 6; s++) {
            f16x8 bfr = *(const f16x8*)(Wp + ((s * 4 + t) * 64 + lane) * 8);
            acc = __builtin_amdgcn_mfma_f32_16x16x32_f16(afr[s], bfr, acc, 0, 0, 0);
        }
        int col = (t << 4) + (lane & 15);
        float bv = bias[col];
#pragma unroll
        for (int rg = 0; rg < 4; rg++) {
            float v = acc[rg] + bv;
            z[(size_t)(orow + rg) * C_OUT + col] = f2h(v > 0.f ? v : (expf(v) - 1.f));
        }
    }
}

// ---------------- Pool: CSR gather-reduce, one batch per block (z L2 affinity) ----------
__global__ void pool_csr_kernel(const ushort_t* __restrict__ z, const int* __restrict__ rowptr,
                                const int2* __restrict__ cn, float* __restrict__ out) {
    int bid = blockIdx.x;
    int b = bid & 3;
    int r = (bid >> 2) * 8 + (threadIdx.x >> 5);
    int c2 = threadIdx.x & 31;   // channels 2c2, 2c2+1
    if (r >= M_POOL) return;
    const char* zb = (const char*)z + (size_t)b * ZH * 2;
    unsigned coff = (unsigned)c2 << 2;
    float s0 = 0.f, s1 = 0.f;
    int p0 = rowptr[N_NODES + r], p1 = rowptr[N_NODES + r + 1];
    for (int p = p0; p < p1; ++p) {
        int2 e = cn[p];
        float v = __int_as_float(e.y);
        unsigned u = *(const unsigned*)(zb + (((unsigned)e.x << 7) + coff));
        s0 += h2f((ushort_t)u) * v;
        s1 += h2f((ushort_t)(u >> 16)) * v;
    }
    size_t idx = (size_t)b * M_POOL * C_OUT + (size_t)r * C_OUT + 2 * c2;
    *(float2*)&out[idx] = make_float2(s0, s1);
}

extern "C" void kernel_launch(void* const* d_in, const int* in_sizes, int n_in,
                              void* d_out, int out_size, void* d_ws, size_t ws_size,
                              hipStream_t stream) {
    const float* x    = (const float*)d_in[0];
    const int*   ei   = (const int*)d_in[1];
    const int*   prow = (const int*)d_in[2];
    const int*   pcol = (const int*)d_in[3];
    const float* pval = (const float*)d_in[4];
    const float* W    = (const float*)d_in[5];
    const float* bias = (const float*)d_in[6];
    const int E = in_sizes[1] / 2;
    const int P = in_sizes[2];
    const int* row = ei;
    const int* col = ei + E;
    const int EP_MAX = E + 7 * N_NODES + P;  // 8-padded CSR upper bound

    char* ws = (char*)d_ws;
    size_t o = 0;
    auto alloc = [&](size_t bytes) -> char* {
        char* p = ws + o;
        o += (bytes + 255) & ~(size_t)255;
        return p;
    };
    int nb = (NT_ROWS + 255) / 256;
    int*   deg    = (int*)alloc((size_t)NT_ROWS * 4);
    int*   degp   = (int*)alloc((size_t)NT_ROWS * 4);
    float* dis    = (float*)alloc((size_t)N_NODES * 4);
    int*   rowptr = (int*)alloc((size_t)(NT_ROWS + 1) * 4);
    int*   slot   = (int*)alloc((size_t)(E + P) * 4);
    int*   bsum   = (int*)alloc((size_t)nb * 4);
    int2*  cn     = (int2*)alloc((size_t)EP_MAX * 8);
    ushort_t* Wp  = (ushort_t*)alloc((size_t)K_CHEB * 4 * 64 * 8 * 2);
    ushort_t* xh  = (ushort_t*)alloc((size_t)B_SZ * NS32 * 2);
    ushort_t* hA  = (ushort_t*)alloc((size_t)B_SZ * NS32 * 2);  // T1
    ushort_t* hB  = (ushort_t*)alloc((size_t)B_SZ * NS32 * 2);  // T2
    ushort_t* hC  = (ushort_t*)alloc((size_t)B_SZ * NS32 * 2);  // T3
    ushort_t* hD  = (ushort_t*)alloc((size_t)B_SZ * NS32 * 2);  // T4
    ushort_t* hE  = (ushort_t*)alloc((size_t)B_SZ * NS32 * 2);  // T5
    ushort_t* z   = (ushort_t*)alloc((size_t)B_SZ * ZH * 2);

    // combined CSR build
    zero_deg_kernel<<<nb, 256, 0, stream>>>(deg);
    deg_slot_kernel<<<(E + P + 255) / 256, 256, 0, stream>>>(row, prow, deg, slot, E, P);
    disdegp_kernel<<<nb, 256, 0, stream>>>(deg, dis, degp);
    block_sum_kernel<<<nb, 256, 0, stream>>>(degp, bsum, NT_ROWS);
    scan_bsum_kernel<<<1, 256, 0, stream>>>(bsum, nb, rowptr, NT_ROWS);
    rowptr_kernel<<<nb, 256, 0, stream>>>(degp, bsum, rowptr, NT_ROWS);
    pad_fill_kernel<<<(N_NODES + 255) / 256, 256, 0, stream>>>(deg, rowptr, cn);
    place_all_kernel<<<(E + P + 255) / 256, 256, 0, stream>>>(row, col, prow, pcol, pval, dis,
                                                              rowptr, slot, cn, E, P);
    // W pack + x cast
    packW_kernel<<<(K_CHEB * 4 * 64 * 8 + 255) / 256, 256, 0, stream>>>(W, Wp);
    int n2 = (int)(B_SZ * NS32 / 2);
    cast_h_kernel<<<(n2 + 255) / 256, 256, 0, stream>>>(x, (unsigned int*)xh, n2);

    int prop_blocks = ((N_NODES + 63) / 64) * B_SZ;  // 782 * 4 = 3128
    int gemm_blocks = (B_SZ * N_NODES) / 64;         // 3125

    // Chebyshev chain: T1..T5 all kept
    prop_kernel<<<prop_blocks, 256, 0, stream>>>(xh, nullptr, hA, rowptr, cn, 1.0f);
    prop_kernel<<<prop_blocks, 256, 0, stream>>>(hA, xh, hB, rowptr, cn, 2.0f);
    prop_kernel<<<prop_blocks, 256, 0, stream>>>(hB, hA, hC, rowptr, cn, 2.0f);
    prop_kernel<<<prop_blocks, 256, 0, stream>>>(hC, hB, hD, rowptr, cn, 2.0f);
    prop_kernel<<<prop_blocks, 256, 0, stream>>>(hD, hC, hE, rowptr, cn, 2.0f);
    // z = ELU([x,T1..T5] @ W + bias), single pass
    gemm_mfma_kernel<<<gemm_blocks, 256, 0, stream>>>(xh, hA, hB, hC, hD, hE, Wp, bias, z);
    // pool (one batch per block)
    pool_csr_kernel<<<((M_POOL + 7) / 8) * B_SZ, 256, 0, stream>>>(z, rowptr, cn,
                                                                   (float*)d_out);
}

// Round 15
// 253.640 us; speedup vs baseline: 2.3393x; 1.0075x over previous
//
#include <hip/hip_runtime.h>
#include <hip/hip_fp16.h>
#include <cstdint>

#define N_NODES 50000
#define B_SZ 4
#define C_IN 32
#define C_OUT 64
#define K_CHEB 6
#define M_POOL 12500
#define NT_ROWS (N_NODES + M_POOL)
#define NS32 ((size_t)N_NODES * C_IN)
#define ZH ((size_t)N_NODES * C_OUT)   // z elements per batch (fp16)
#define CN_CAP 2048                    // LDS-staged cn entries per block (16 KB)
#define DSTR 16                        // deg counter stride: one per 64B line (anti-serialize)

typedef _Float16 f16x8 __attribute__((ext_vector_type(8)));
typedef float f32x4 __attribute__((ext_vector_type(4)));
typedef unsigned short ushort_t;

__device__ __forceinline__ unsigned short f2h(float f) {
    union { _Float16 h; unsigned short u; } v;
    v.h = (_Float16)f;
    return v.u;
}

__device__ __forceinline__ float h2f(unsigned short u) {
    union { unsigned short u; _Float16 h; } v;
    v.u = u;
    return (float)v.h;
}

__device__ __forceinline__ __half2 u2h2(unsigned u) { return __builtin_bit_cast(__half2, u); }
__device__ __forceinline__ unsigned h22u(__half2 h) { return __builtin_bit_cast(unsigned, h); }

// ---------------- zero kernel for the line-padded degree array ----------------
__global__ void zero_deg_kernel(int* __restrict__ deg_s) {
    int i = blockIdx.x * 256 + threadIdx.x;
    if (i < NT_ROWS * DSTR) deg_s[i] = 0;
}

// ---------------- Combined CSR build (rows 0..N-1 = graph, N..N+M-1 = pool) ----------------
// deg counters padded to one per 64B line: same-line atomic chains drop 272 -> ~17
__global__ void deg_slot_kernel(const int* __restrict__ row, const int* __restrict__ prow,
                                int* __restrict__ deg_s, int* __restrict__ slot, int E, int P) {
    int e = blockIdx.x * blockDim.x + threadIdx.x;
    if (e < E) slot[e] = atomicAdd(&deg_s[row[e] * DSTR], 1);
    else if (e < E + P) slot[e] = atomicAdd(&deg_s[(N_NODES + prow[e - E]) * DSTR], 1);
}

// dis for graph rows; padded degree: graph rows pad to multiple of 8, pool rows unpadded
__global__ void disdegp_kernel(const int* __restrict__ deg_s, float* __restrict__ dis,
                               int* __restrict__ degp) {
    int i = blockIdx.x * blockDim.x + threadIdx.x;
    if (i < N_NODES) {
        int d = deg_s[i * DSTR];
        dis[i] = d > 0 ? rsqrtf((float)d) : 0.f;
        degp[i] = (d + 7) & ~7;
    } else if (i < NT_ROWS) {
        degp[i] = deg_s[i * DSTR];
    }
}

__global__ void block_sum_kernel(const int* __restrict__ degp, int* __restrict__ bsum, int N) {
    __shared__ int sm[256];
    int i = blockIdx.x * 256 + threadIdx.x;
    sm[threadIdx.x] = (i < N) ? degp[i] : 0;
    __syncthreads();
    for (int s = 128; s > 0; s >>= 1) {
        if (threadIdx.x < s) sm[threadIdx.x] += sm[threadIdx.x + s];
        __syncthreads();
    }
    if (threadIdx.x == 0) bsum[blockIdx.x] = sm[0];
}

// parallel exclusive scan over nb (<=256) block sums, one block
__global__ void scan_bsum_kernel(int* bsum, int nb, int* rowptr, int N) {
    __shared__ int sm[256];
    int t = threadIdx.x;
    int v = (t < nb) ? bsum[t] : 0;
    sm[t] = v;
    __syncthreads();
    for (int off = 1; off < 256; off <<= 1) {
        int u = (t >= off) ? sm[t - off] : 0;
        __syncthreads();
        sm[t] += u;
        __syncthreads();
    }
    if (t < nb) bsum[t] = sm[t] - v;   // exclusive
    if (t == 0) rowptr[N] = sm[255];   // grand total
}

__global__ void rowptr_kernel(const int* __restrict__ degp, const int* __restrict__ bsum,
                              int* __restrict__ rowptr, int N) {
    __shared__ int sm[256];
    int i = blockIdx.x * 256 + threadIdx.x;
    sm[threadIdx.x] = (i < N) ? degp[i] : 0;
    __syncthreads();
    if (threadIdx.x == 0) {
        int run = bsum[blockIdx.x];
        for (int t = 0; t < 256; t++) { int v = sm[t]; sm[t] = run; run += v; }
    }
    __syncthreads();
    if (i < N) rowptr[i] = sm[threadIdx.x];
}

// zero only the pad slots of graph rows
__global__ void pad_fill_kernel(const int* __restrict__ deg_s, const int* __restrict__ rowptr,
                                int2* __restrict__ cn) {
    int r = blockIdx.x * blockDim.x + threadIdx.x;
    if (r >= N_NODES) return;
    int p = rowptr[r] + deg_s[r * DSTR];
    int p1 = rowptr[r + 1];
    for (; p < p1; ++p) cn[p] = make_int2(0, 0);
}

// atomic-free placement. Graph rows: cn.y = packed half2(norm,norm). Pool rows: cn.y = f32 bits.
__global__ void place_all_kernel(const int* __restrict__ row, const int* __restrict__ col,
                                 const int* __restrict__ prow, const int* __restrict__ pcol,
                                 const float* __restrict__ pval, const float* __restrict__ dis,
                                 const int* __restrict__ rowptr, const int* __restrict__ slot,
                                 int2* __restrict__ cn, int E, int P) {
    int e = blockIdx.x * blockDim.x + threadIdx.x;
    if (e < E) {
        int r = row[e], c = col[e];
        float nm = -dis[r] * dis[c];
        unsigned h = f2h(nm);
        cn[rowptr[r] + slot[e]] = make_int2(c, (int)(h | (h << 16)));
    } else if (e < E + P) {
        int i = e - E;
        int r = N_NODES + prow[i];
        cn[rowptr[r] + slot[e]] = make_int2(pcol[i], __float_as_int(pval[i]));
    }
}

// ---------------- fp32 -> fp16 cast ----------------
__global__ void cast_h_kernel(const float* __restrict__ in, unsigned int* __restrict__ out,
                              int n2) {
    int i = blockIdx.x * 256 + threadIdx.x;
    if (i < n2) {
        unsigned a = f2h(in[2 * i]), b = f2h(in[2 * i + 1]);
        out[i] = a | (b << 16);
    }
}

// ---------------- Chebyshev propagation v14: LDS cn + 8-deep pipeline, 8 waves/SIMD ----------
// Block = 64 rows x ONE batch (bid&3 -> per-XCD slice). VGPR-trimmed body (~62 regs):
// off[8]+n[8] from LDS, 8 independent 16B gathers in flight, 32 hfma2.
__global__ void __launch_bounds__(256, 8)
prop_kernel(const ushort_t* __restrict__ hf, const ushort_t* __restrict__ p2f,
            ushort_t* __restrict__ outf,
            const int* __restrict__ rowptr, const int2* __restrict__ cn, float alpha) {
    __shared__ int2 lcn[CN_CAP];
    int bid = blockIdx.x;
    int b = bid & 3;
    int grp = bid >> 2;            // [0, 782)
    int r0 = grp * 64;
    int rend = r0 + 64 > N_NODES ? N_NODES : r0 + 64;
    int pbase = rowptr[r0];
    int pend = rowptr[rend];
    int cnt = pend - pbase;
    bool use_lds = (cnt <= CN_CAP);
    if (use_lds) {
        for (int i = threadIdx.x; i < cnt; i += 256) lcn[i] = cn[pbase + i];
    }
    __syncthreads();

    int lr = threadIdx.x >> 2;     // 0..63
    int cs = threadIdx.x & 3;      // channel oct
    int r = r0 + lr;
    if (r >= N_NODES) return;
    const char* hb = (const char*)hf + (size_t)b * NS32 * 2;
    unsigned coff = (unsigned)cs * 16u;
    __half2 a0 = __float2half2_rn(0.f), a1 = a0, a2 = a0, a3 = a0;

    if (use_lds) {
        int p0 = rowptr[r] - pbase, p1 = rowptr[r + 1] - pbase;
        for (int p = p0; p < p1; p += 8) {
            unsigned off[8];
            __half2 n[8];
#pragma unroll
            for (int i = 0; i < 8; i++) {
                int2 e = lcn[p + i];
                off[i] = ((unsigned)e.x << 6) + coff;
                n[i] = u2h2((unsigned)e.y);
            }
            uint4 v[8];
#pragma unroll
            for (int i = 0; i < 8; i++) v[i] = *(const uint4*)(hb + off[i]);
#pragma unroll
            for (int i = 0; i < 8; i++) {
                a0 = __hfma2(u2h2(v[i].x), n[i], a0);
                a1 = __hfma2(u2h2(v[i].y), n[i], a1);
                a2 = __hfma2(u2h2(v[i].z), n[i], a2);
                a3 = __hfma2(u2h2(v[i].w), n[i], a3);
            }
        }
    } else {
        int p0 = rowptr[r], p1 = rowptr[r + 1];
        for (int p = p0; p < p1; p += 8) {
            unsigned off[8];
            __half2 n[8];
#pragma unroll
            for (int i = 0; i < 8; i++) {
                int2 e = cn[p + i];
                off[i] = ((unsigned)e.x << 6) + coff;
                n[i] = u2h2((unsigned)e.y);
            }
            uint4 v[8];
#pragma unroll
            for (int i = 0; i < 8; i++) v[i] = *(const uint4*)(hb + off[i]);
#pragma unroll
            for (int i = 0; i < 8; i++) {
                a0 = __hfma2(u2h2(v[i].x), n[i], a0);
                a1 = __hfma2(u2h2(v[i].y), n[i], a1);
                a2 = __hfma2(u2h2(v[i].z), n[i], a2);
                a3 = __hfma2(u2h2(v[i].w), n[i], a3);
            }
        }
    }

    unsigned ooff = ((unsigned)r << 6) + coff;
    uint4 o;
    if (p2f) {
        __half2 al2 = __float2half2_rn(alpha);
        uint4 pv = *(const uint4*)((const char*)p2f + (size_t)b * NS32 * 2 + ooff);
        o.x = h22u(__hfma2(a0, al2, __hneg2(u2h2(pv.x))));
        o.y = h22u(__hfma2(a1, al2, __hneg2(u2h2(pv.y))));
        o.z = h22u(__hfma2(a2, al2, __hneg2(u2h2(pv.z))));
        o.w = h22u(__hfma2(a3, al2, __hneg2(u2h2(pv.w))));
    } else {
        o.x = h22u(a0); o.y = h22u(a1); o.z = h22u(a2); o.w = h22u(a3);
    }
    *(uint4*)((char*)outf + (size_t)b * NS32 * 2 + ooff) = o;
}

// ---------------- W pack: [s][t][lane][j] fp16 fragment order ----------------
__global__ void packW_kernel(const float* __restrict__ W, ushort_t* __restrict__ Wp) {
    int i = blockIdx.x * 256 + threadIdx.x;
    if (i >= K_CHEB * 4 * 64 * 8) return;
    int j = i & 7;
    int lane = (i >> 3) & 63;
    int t = (i >> 9) & 3;
    int s = i >> 11;
    int k = (lane >> 4) * 8 + j;
    int col = t * 16 + (lane & 15);
    Wp[i] = f2h(W[((size_t)s * C_IN + k) * C_OUT + col]);
}

// ---------------- Single fused 6-source MFMA GEMM + bias + ELU -> fp16 z ----------------
__global__ void gemm_mfma_kernel(const ushort_t* __restrict__ T0, const ushort_t* __restrict__ T1,
                                 const ushort_t* __restrict__ T2, const ushort_t* __restrict__ T3,
                                 const ushort_t* __restrict__ T4, const ushort_t* __restrict__ T5,
                                 const ushort_t* __restrict__ Wp,
                                 const float* __restrict__ bias, ushort_t* __restrict__ z) {
    int lane = threadIdx.x & 63;
    int wave = (blockIdx.x << 2) + (threadIdx.x >> 6);
    int r0 = wave << 4;
    int ga = r0 + (lane & 15);
    int koff = (lane >> 4) * 8;
    const ushort_t* Ts[6] = {T0, T1, T2, T3, T4, T5};

    f16x8 afr[6];
#pragma unroll
    for (int s = 0; s < 6; s++)
        afr[s] = *(const f16x8*)(Ts[s] + (size_t)ga * C_IN + koff);

    int orow = r0 + ((lane >> 4) << 2);
#pragma unroll
    for (int t = 0; t < 4; t++) {
        f32x4 acc = {0.f, 0.f, 0.f, 0.f};
#pragma unroll
        for (int s = 0; s < 6; s++) {
            f16x8 bfr = *(const f16x8*)(Wp + ((s * 4 + t) * 64 + lane) * 8);
            acc = __builtin_amdgcn_mfma_f32_16x16x32_f16(afr[s], bfr, acc, 0, 0, 0);
        }
        int col = (t << 4) + (lane & 15);
        float bv = bias[col];
#pragma unroll
        for (int rg = 0; rg < 4; rg++) {
            float v = acc[rg] + bv;
            z[(size_t)(orow + rg) * C_OUT + col] = f2h(v > 0.f ? v : (expf(v) - 1.f));
        }
    }
}

// ---------------- Pool: CSR gather-reduce, one batch per block (z L2 affinity) ----------
__global__ void pool_csr_kernel(const ushort_t* __restrict__ z, const int* __restrict__ rowptr,
                                const int2* __restrict__ cn, float* __restrict__ out) {
    int bid = blockIdx.x;
    int b = bid & 3;
    int r = (bid >> 2) * 8 + (threadIdx.x >> 5);
    int c2 = threadIdx.x & 31;   // channels 2c2, 2c2+1
    if (r >= M_POOL) return;
    const char* zb = (const char*)z + (size_t)b * ZH * 2;
    unsigned coff = (unsigned)c2 << 2;
    float s0 = 0.f, s1 = 0.f;
    int p0 = rowptr[N_NODES + r], p1 = rowptr[N_NODES + r + 1];
    for (int p = p0; p < p1; ++p) {
        int2 e = cn[p];
        float v = __int_as_float(e.y);
        unsigned u = *(const unsigned*)(zb + (((unsigned)e.x << 7) + coff));
        s0 += h2f((ushort_t)u) * v;
        s1 += h2f((ushort_t)(u >> 16)) * v;
    }
    size_t idx = (size_t)b * M_POOL * C_OUT + (size_t)r * C_OUT + 2 * c2;
    *(float2*)&out[idx] = make_float2(s0, s1);
}

extern "C" void kernel_launch(void* const* d_in, const int* in_sizes, int n_in,
                              void* d_out, int out_size, void* d_ws, size_t ws_size,
                              hipStream_t stream) {
    const float* x    = (const float*)d_in[0];
    const int*   ei   = (const int*)d_in[1];
    const int*   prow = (const int*)d_in[2];
    const int*   pcol = (const int*)d_in[3];
    const float* pval = (const float*)d_in[4];
    const float* W    = (const float*)d_in[5];
    const float* bias = (const float*)d_in[6];
    const int E = in_sizes[1] / 2;
    const int P = in_sizes[2];
    const int* row = ei;
    const int* col = ei + E;
    const int EP_MAX = E + 7 * N_NODES + P;  // 8-padded CSR upper bound

    char* ws = (char*)d_ws;
    size_t o = 0;
    auto alloc = [&](size_t bytes) -> char* {
        char* p = ws + o;
        o += (bytes + 255) & ~(size_t)255;
        return p;
    };
    int nb = (NT_ROWS + 255) / 256;
    int*   deg_s  = (int*)alloc((size_t)NT_ROWS * DSTR * 4);  // 4 MB, line-padded counters
    int*   degp   = (int*)alloc((size_t)NT_ROWS * 4);
    float* dis    = (float*)alloc((size_t)N_NODES * 4);
    int*   rowptr = (int*)alloc((size_t)(NT_ROWS + 1) * 4);
    int*   slot   = (int*)alloc((size_t)(E + P) * 4);
    int*   bsum   = (int*)alloc((size_t)nb * 4);
    int2*  cn     = (int2*)alloc((size_t)EP_MAX * 8);
    ushort_t* Wp  = (ushort_t*)alloc((size_t)K_CHEB * 4 * 64 * 8 * 2);
    ushort_t* xh  = (ushort_t*)alloc((size_t)B_SZ * NS32 * 2);
    ushort_t* hA  = (ushort_t*)alloc((size_t)B_SZ * NS32 * 2);  // T1
    ushort_t* hB  = (ushort_t*)alloc((size_t)B_SZ * NS32 * 2);  // T2
    ushort_t* hC  = (ushort_t*)alloc((size_t)B_SZ * NS32 * 2);  // T3
    ushort_t* hD  = (ushort_t*)alloc((size_t)B_SZ * NS32 * 2);  // T4
    ushort_t* hE  = (ushort_t*)alloc((size_t)B_SZ * NS32 * 2);  // T5
    ushort_t* z   = (ushort_t*)alloc((size_t)B_SZ * ZH * 2);

    // combined CSR build
    zero_deg_kernel<<<(NT_ROWS * DSTR + 255) / 256, 256, 0, stream>>>(deg_s);
    deg_slot_kernel<<<(E + P + 255) / 256, 256, 0, stream>>>(row, prow, deg_s, slot, E, P);
    disdegp_kernel<<<nb, 256, 0, stream>>>(deg_s, dis, degp);
    block_sum_kernel<<<nb, 256, 0, stream>>>(degp, bsum, NT_ROWS);
    scan_bsum_kernel<<<1, 256, 0, stream>>>(bsum, nb, rowptr, NT_ROWS);
    rowptr_kernel<<<nb, 256, 0, stream>>>(degp, bsum, rowptr, NT_ROWS);
    pad_fill_kernel<<<(N_NODES + 255) / 256, 256, 0, stream>>>(deg_s, rowptr, cn);
    place_all_kernel<<<(E + P + 255) / 256, 256, 0, stream>>>(row, col, prow, pcol, pval, dis,
                                                              rowptr, slot, cn, E, P);
    // W pack + x cast
    packW_kernel<<<(K_CHEB * 4 * 64 * 8 + 255) / 256, 256, 0, stream>>>(W, Wp);
    int n2 = (int)(B_SZ * NS32 / 2);
    cast_h_kernel<<<(n2 + 255) / 256, 256, 0, stream>>>(x, (unsigned int*)xh, n2);

    int prop_blocks = ((N_NODES + 63) / 64) * B_SZ;  // 782 * 4 = 3128
    int gemm_blocks = (B_SZ * N_NODES) / 64;         // 3125

    // Chebyshev chain: T1..T5 all kept
    prop_kernel<<<prop_blocks, 256, 0, stream>>>(xh, nullptr, hA, rowptr, cn, 1.0f);
    prop_kernel<<<prop_blocks, 256, 0, stream>>>(hA, xh, hB, rowptr, cn, 2.0f);
    prop_kernel<<<prop_blocks, 256, 0, stream>>>(hB, hA, hC, rowptr, cn, 2.0f);
    prop_kernel<<<prop_blocks, 256, 0, stream>>>(hC, hB, hD, rowptr, cn, 2.0f);
    prop_kernel<<<prop_blocks, 256, 0, stream>>>(hD, hC, hE, rowptr, cn, 2.0f);
    // z = ELU([x,T1..T5] @ W + bias), single pass
    gemm_mfma_kernel<<<gemm_blocks, 256, 0, stream>>>(xh, hA, hB, hC, hD, hE, Wp, bias, z);
    // pool (one batch per block)
    pool_csr_kernel<<<((M_POOL + 7) / 8) * B_SZ, 256, 0, stream>>>(z, rowptr, cn,
                                                                   (float*)d_out);
}